// Round 3
// baseline (518.958 us; speedup 1.0000x reference)
//
#include <hip/hip_runtime.h>
#include <hip/hip_bf16.h>

#define DIMD 512
#define NEXP 8
#define HIDN 2048
#define NTOK 4096
#define NASG 8192
#define M_BLK 32
#define HCHK 128
#define NGROUP 4
#define HPERG (HIDN / NGROUP)   // 512 hidden dims per wave-group

typedef short bf16x8 __attribute__((ext_vector_type(8)));
typedef float f32x4 __attribute__((ext_vector_type(4)));

__device__ inline unsigned short f2bf(float f) {
  __hip_bfloat16 h = __float2bfloat16(f);
  return __builtin_bit_cast(unsigned short, h);
}

// ---------- W [E][R][C] fp32 -> WT [E][C][R] bf16 (tiled transpose) ----------
__global__ __launch_bounds__(256) void transpose_w_kernel(const float* __restrict__ src,
                                                          unsigned short* __restrict__ dst,
                                                          int R, int C) {
  __shared__ float tile[64][65];
  int e = blockIdx.z;
  int c0 = blockIdx.x * 64, r0 = blockIdx.y * 64;
  const float* s = src + (size_t)e * R * C;
  unsigned short* d = dst + (size_t)e * R * C;
  for (int i = threadIdx.x; i < 4096; i += 256) {
    int r = i >> 6, c = i & 63;
    tile[r][c] = s[(size_t)(r0 + r) * C + (c0 + c)];
  }
  __syncthreads();
  // vectorized write: two consecutive r packed into one u32
  for (int i = threadIdx.x; i < 2048; i += 256) {
    int c = i >> 5;
    int r = (i & 31) * 2;
    unsigned lo = f2bf(tile[r][c]);
    unsigned hi = f2bf(tile[r + 1][c]);
    *reinterpret_cast<unsigned*>(d + (size_t)(c0 + c) * R + (r0 + r)) = lo | (hi << 16);
  }
}

// ---------- router: logits, softmax, top-2, renorm, counts; also emits x in bf16 ----------
__global__ __launch_bounds__(256) void router_kernel(const float* __restrict__ x,
                                                     const float* __restrict__ Wr,
                                                     const float* __restrict__ br,
                                                     int* __restrict__ cnt,
                                                     int* __restrict__ tidx,
                                                     float* __restrict__ tw,
                                                     unsigned short* __restrict__ xb) {
  int lane = threadIdx.x & 63;
  int n = blockIdx.x * 4 + (threadIdx.x >> 6);
  const float* xr = x + (size_t)n * DIMD;
  unsigned short* xbr = xb + (size_t)n * DIMD;
  float acc[NEXP];
#pragma unroll
  for (int e = 0; e < NEXP; ++e) acc[e] = 0.f;
#pragma unroll
  for (int it = 0; it < DIMD / 64; ++it) {
    int d = lane + it * 64;
    float xv = xr[d];
    xbr[d] = f2bf(xv);                       // fused x -> bf16
    const float* wr = Wr + (size_t)d * NEXP;
#pragma unroll
    for (int e = 0; e < NEXP; ++e) acc[e] += xv * wr[e];
  }
#pragma unroll
  for (int e = 0; e < NEXP; ++e) {
    float v = acc[e];
#pragma unroll
    for (int off = 32; off > 0; off >>= 1) v += __shfl_xor(v, off, 64);
    acc[e] = v + br[e];
  }
  if (lane == 0) {
    float m = acc[0];
    for (int e = 1; e < NEXP; ++e) m = fmaxf(m, acc[e]);
    float p[NEXP], s = 0.f;
    for (int e = 0; e < NEXP; ++e) { p[e] = expf(acc[e] - m); s += p[e]; }
    float inv = 1.f / s;
    for (int e = 0; e < NEXP; ++e) p[e] *= inv;
    int i0 = 0; float p0 = p[0];
    for (int e = 1; e < NEXP; ++e) if (p[e] > p0) { p0 = p[e]; i0 = e; }
    int i1 = (i0 == 0) ? 1 : 0; float p1 = p[i1];
    for (int e = 0; e < NEXP; ++e) if (e != i0 && p[e] > p1) { p1 = p[e]; i1 = e; }
    // reference renormalizes by softmax over the top-2 *probabilities*
    float t = expf(p1 - p0);
    float w0 = 1.f / (1.f + t);
    tidx[2 * n] = i0; tidx[2 * n + 1] = i1;
    tw[2 * n] = w0; tw[2 * n + 1] = t * w0;
    atomicAdd(&cnt[i0], 1);
    atomicAdd(&cnt[i1], 1);
  }
}

// ---------- offsets + lb_loss/load tail ----------
__global__ void finalize_kernel(const int* __restrict__ cnt, int* __restrict__ off,
                                int* __restrict__ cur, float* __restrict__ out_tail) {
  if (threadIdx.x == 0) {
    int o = 0;
    float lb = 0.f;
    for (int e = 0; e < NEXP; ++e) {
      off[e] = o; o += cnt[e];
      float l = (float)cnt[e] / (float)NASG;
      out_tail[1 + e] = l;
      float dd = l - 0.125f;
      lb += dd * dd;
      cur[e] = 0;
    }
    off[NEXP] = o;
    out_tail[0] = lb;
  }
}

// ---------- scatter assignment ids into per-expert lists ----------
__global__ __launch_bounds__(256) void scatter_kernel(const int* __restrict__ tidx,
                                                      const int* __restrict__ off,
                                                      int* __restrict__ cur,
                                                      int* __restrict__ list) {
  int a = blockIdx.x * 256 + threadIdx.x;
  if (a < NASG) {
    int e = tidx[a];
    int pos = off[e] + atomicAdd(&cur[e], 1);
    list[pos] = a;
  }
}

// ---------- grouped expert MLP: 16 waves, hidden split in-block, LDS reduce ----------
// Yw[a] = w_a * (gelu(x W1 + b1) W2 + b2); no global atomics, deterministic.
__global__ __launch_bounds__(1024, 4) void mlp_kernel(
    const unsigned short* __restrict__ xb,
    const unsigned short* __restrict__ w1t,   // [E][HIDN][DIMD] bf16 (W1 transposed)
    const unsigned short* __restrict__ w2t,   // [E][DIMD][HIDN] bf16 (W2 transposed)
    const float* __restrict__ b1,
    const float* __restrict__ b2,
    const int* __restrict__ off,
    const int* __restrict__ list,
    const float* __restrict__ tw,
    float* __restrict__ Yw) {
  int e = blockIdx.x;                       // bid%8 == expert -> XCD-pinned L2 reuse
  int cnt_e = off[e + 1] - off[e];
  int r0 = blockIdx.y * M_BLK;
  if (r0 >= cnt_e) return;
  int offe = off[e];

  __shared__ unsigned short Xs[M_BLK][DIMD];           // 32 KB, XOR-swizzled rows
  __shared__ unsigned short Hs[NGROUP][M_BLK][HCHK];   // 32 KB, group-private, swizzled
  __shared__ float Yacc[M_BLK][DIMD];                  // 64 KB, swizzled

  int tid = threadIdx.x;
  int wv = tid >> 6, lane = tid & 63;
  int g = wv >> 2;          // hidden-split group 0..3
  int w4 = wv & 3;          // wave within group

  char* XsB = (char*)Xs;
  char* HsB = (char*)Hs + g * (M_BLK * HCHK * 2);
  char* YaB = (char*)Yacc;

  // stage X rows (gathered by token) into swizzled LDS
  for (int u = tid; u < M_BLK * DIMD / 8; u += 1024) {
    int row = u >> 6, cu = u & 63;
    uint4 val = make_uint4(0u, 0u, 0u, 0u);
    int rr = r0 + row;
    if (rr < cnt_e) {
      int tok = list[offe + rr] >> 1;
      val = *reinterpret_cast<const uint4*>(xb + (size_t)tok * DIMD + cu * 8);
    }
    int byte = (row * 1024 + cu * 16) ^ ((row & 7) << 4);
    *reinterpret_cast<uint4*>(XsB + byte) = val;
  }
  __syncthreads();

  const unsigned short* w1e = w1t + (size_t)e * HIDN * DIMD;
  const unsigned short* w2e = w2t + (size_t)e * DIMD * HIDN;
  const float* b1e = b1 + e * HIDN;
  const float* b2e = b2 + e * DIMD;

  f32x4 zero = {0.f, 0.f, 0.f, 0.f};
  f32x4 acc[2][8];
  for (int m = 0; m < 2; ++m)
    for (int nf = 0; nf < 8; ++nf) acc[m][nf] = zero;

  int row0 = lane & 15;      // A row (also fragment column index)
  int row1 = row0 + 16;
  int kq = lane >> 4;        // quarter-wave -> k sub-block
  int h0 = g * HPERG;

  for (int hc = h0; hc < h0 + HPERG; hc += HCHK) {
    // GEMM1: this wave computes H[0..32)[w4*32 .. w4*32+32) of group g's chunk
    f32x4 hacc[2][2];
    hacc[0][0] = zero; hacc[0][1] = zero; hacc[1][0] = zero; hacc[1][1] = zero;
    int colg = hc + w4 * 32 + row0;
#pragma unroll
    for (int kk = 0; kk < 16; ++kk) {
      int kb = kk * 64 + kq * 16;
      bf16x8 a0 = *reinterpret_cast<const bf16x8*>(XsB + ((row0 * 1024 + kb) ^ ((row0 & 7) << 4)));
      bf16x8 a1 = *reinterpret_cast<const bf16x8*>(XsB + ((row1 * 1024 + kb) ^ ((row1 & 7) << 4)));
      int kg = kk * 32 + kq * 8;
      bf16x8 b0  = *reinterpret_cast<const bf16x8*>(w1e + (size_t)colg * DIMD + kg);
      bf16x8 b1f = *reinterpret_cast<const bf16x8*>(w1e + (size_t)(colg + 16) * DIMD + kg);
      hacc[0][0] = __builtin_amdgcn_mfma_f32_16x16x32_bf16(a0, b0,  hacc[0][0], 0, 0, 0);
      hacc[0][1] = __builtin_amdgcn_mfma_f32_16x16x32_bf16(a0, b1f, hacc[0][1], 0, 0, 0);
      hacc[1][0] = __builtin_amdgcn_mfma_f32_16x16x32_bf16(a1, b0,  hacc[1][0], 0, 0, 0);
      hacc[1][1] = __builtin_amdgcn_mfma_f32_16x16x32_bf16(a1, b1f, hacc[1][1], 0, 0, 0);
    }
    __syncthreads();   // prior GEMM2 reads of this group's Hs are done
    // bias + exact gelu, store bf16 H chunk (group-private)
#pragma unroll
    for (int m = 0; m < 2; ++m) {
#pragma unroll
      for (int nf = 0; nf < 2; ++nf) {
        int cc = w4 * 32 + nf * 16 + row0;
        float bias = b1e[hc + cc];
#pragma unroll
        for (int q = 0; q < 4; ++q) {
          int row = m * 16 + kq * 4 + q;
          float v = hacc[m][nf][q] + bias;
          float gl = 0.5f * v * (1.f + erff(v * 0.70710678118654752f));
          int byte = (row * 256 + cc * 2) ^ ((row & 7) << 4);
          *reinterpret_cast<unsigned short*>(HsB + byte) = f2bf(gl);
        }
      }
    }
    __syncthreads();
    // GEMM2: Y[0..32)[w4*128 ..+128) += Hs(g) @ W2T
#pragma unroll
    for (int kk = 0; kk < 4; ++kk) {
      int kb = kk * 64 + kq * 16;
      bf16x8 ha0 = *reinterpret_cast<const bf16x8*>(HsB + ((row0 * 256 + kb) ^ ((row0 & 7) << 4)));
      bf16x8 ha1 = *reinterpret_cast<const bf16x8*>(HsB + ((row1 * 256 + kb) ^ ((row1 & 7) << 4)));
      int kg = hc + kk * 32 + kq * 8;
#pragma unroll
      for (int nf = 0; nf < 8; ++nf) {
        int col = w4 * 128 + nf * 16 + row0;
        bf16x8 bw = *reinterpret_cast<const bf16x8*>(w2e + (size_t)col * HIDN + kg);
        acc[0][nf] = __builtin_amdgcn_mfma_f32_16x16x32_bf16(ha0, bw, acc[0][nf], 0, 0, 0);
        acc[1][nf] = __builtin_amdgcn_mfma_f32_16x16x32_bf16(ha1, bw, acc[1][nf], 0, 0, 0);
      }
    }
  }

  // staged deterministic reduction of group partials into Yacc
  for (int gg = 0; gg < NGROUP; ++gg) {
    __syncthreads();
    if (g == gg) {
#pragma unroll
      for (int m = 0; m < 2; ++m) {
#pragma unroll
        for (int nf = 0; nf < 8; ++nf) {
#pragma unroll
          for (int q = 0; q < 4; ++q) {
            int row = m * 16 + kq * 4 + q;
            int col = w4 * 128 + nf * 16 + row0;
            int byte = ((row * DIMD + col) * 4) ^ ((row & 7) << 4);
            float* p = reinterpret_cast<float*>(YaB + byte);
            if (gg == 0) *p = acc[m][nf][q];
            else         *p += acc[m][nf][q];
          }
        }
      }
    }
  }
  __syncthreads();

  // epilogue: weighted + bias write of Y rows (float4)
  for (int u = tid; u < M_BLK * DIMD / 4; u += 1024) {
    int row = u >> 7;
    int c4 = (u & 127) * 4;
    int rr = r0 + row;
    if (rr >= cnt_e) continue;
    int a = list[offe + rr];
    float w = tw[a];
    int byte = ((row * DIMD + c4) * 4) ^ ((row & 7) << 4);
    f32x4 y = *reinterpret_cast<f32x4*>(YaB + byte);
    float4 bb = *reinterpret_cast<const float4*>(b2e + c4);
    float4 o;
    o.x = w * (y[0] + bb.x);
    o.y = w * (y[1] + bb.y);
    o.z = w * (y[2] + bb.z);
    o.w = w * (y[3] + bb.w);
    *reinterpret_cast<float4*>(Yw + (size_t)a * DIMD + c4) = o;
  }
}

// ---------- combine: out[n] = Yw[2n] + Yw[2n+1] ----------
__global__ __launch_bounds__(256) void combine_kernel(const float* __restrict__ Yw,
                                                      float* __restrict__ out) {
  int i = (blockIdx.x * 256 + threadIdx.x) * 4;
  int n = i >> 9;
  int d = i & 511;
  float4 a = *reinterpret_cast<const float4*>(Yw + (size_t)(2 * n) * DIMD + d);
  float4 b = *reinterpret_cast<const float4*>(Yw + (size_t)(2 * n + 1) * DIMD + d);
  float4 o;
  o.x = a.x + b.x; o.y = a.y + b.y; o.z = a.z + b.z; o.w = a.w + b.w;
  *reinterpret_cast<float4*>(out + i) = o;
}

extern "C" void kernel_launch(void* const* d_in, const int* in_sizes, int n_in,
                              void* d_out, int out_size, void* d_ws, size_t ws_size,
                              hipStream_t stream) {
  const float* x  = (const float*)d_in[0];
  const float* Wr = (const float*)d_in[1];
  const float* br = (const float*)d_in[2];
  const float* W1 = (const float*)d_in[3];
  const float* b1 = (const float*)d_in[4];
  const float* W2 = (const float*)d_in[5];
  const float* b2 = (const float*)d_in[6];
  float* out = (float*)d_out;

  char* ws = (char*)d_ws;
  unsigned short* xb  = (unsigned short*)ws;  ws += (size_t)NTOK * DIMD * 2;
  unsigned short* w1t = (unsigned short*)ws;  ws += (size_t)NEXP * HIDN * DIMD * 2;
  unsigned short* w2t = (unsigned short*)ws;  ws += (size_t)NEXP * DIMD * HIDN * 2;
  float* Yw = (float*)ws;                     ws += (size_t)NASG * DIMD * 4;
  float* tw = (float*)ws;                     ws += (size_t)NASG * 4;
  int* tidx = (int*)ws;                       ws += (size_t)NASG * 4;
  int* list = (int*)ws;                       ws += (size_t)NASG * 4;
  int* ctrl = (int*)ws;                       // cnt[8], cur[8], off[9]
  int* cnt = ctrl;
  int* cur = ctrl + 8;
  int* offp = ctrl + 16;

  hipMemsetAsync(ctrl, 0, 32 * sizeof(int), stream);
  transpose_w_kernel<<<dim3(HIDN / 64, DIMD / 64, NEXP), 256, 0, stream>>>(W1, w1t, DIMD, HIDN);
  transpose_w_kernel<<<dim3(DIMD / 64, HIDN / 64, NEXP), 256, 0, stream>>>(W2, w2t, HIDN, DIMD);
  router_kernel<<<NTOK / 4, 256, 0, stream>>>(x, Wr, br, cnt, tidx, tw, xb);
  finalize_kernel<<<1, 64, 0, stream>>>(cnt, offp, cur, out + (size_t)NTOK * DIMD);
  scatter_kernel<<<NASG / 256, 256, 0, stream>>>(tidx, offp, cur, list);
  mlp_kernel<<<dim3(NEXP, NASG / M_BLK), 1024, 0, stream>>>(xb, w1t, w2t, b1, b2, offp, list, tw, Yw);
  combine_kernel<<<2048, 256, 0, stream>>>(Yw, out);
}

// Round 4
// 290.013 us; speedup vs baseline: 1.7894x; 1.7894x over previous
//
#include <hip/hip_runtime.h>
#include <hip/hip_bf16.h>

#define DIMD 512
#define NEXP 8
#define HIDN 2048
#define NTOK 4096
#define NASG 8192

typedef short bf16x8 __attribute__((ext_vector_type(8)));
typedef float f32x4 __attribute__((ext_vector_type(4)));

__device__ inline unsigned short f2bf(float f) {
  __hip_bfloat16 h = __float2bfloat16(f);
  return __builtin_bit_cast(unsigned short, h);
}

__device__ inline void gl16(const void* g, void* l) {
  __builtin_amdgcn_global_load_lds(
      (const __attribute__((address_space(1))) unsigned int*)g,
      (__attribute__((address_space(3))) unsigned int*)l, 16, 0, 0);
}

// ---------- W [E][R][C] fp32 -> WT [E][C][R] bf16 (tiled transpose) ----------
__global__ __launch_bounds__(256) void transpose_w_kernel(const float* __restrict__ src,
                                                          unsigned short* __restrict__ dst,
                                                          int R, int C) {
  __shared__ float tile[64][65];
  int e = blockIdx.z;
  int c0 = blockIdx.x * 64, r0 = blockIdx.y * 64;
  const float* s = src + (size_t)e * R * C;
  unsigned short* d = dst + (size_t)e * R * C;
  for (int i = threadIdx.x; i < 4096; i += 256) {
    int r = i >> 6, c = i & 63;
    tile[r][c] = s[(size_t)(r0 + r) * C + (c0 + c)];
  }
  __syncthreads();
  for (int i = threadIdx.x; i < 2048; i += 256) {
    int c = i >> 5;
    int r = (i & 31) * 2;
    unsigned lo = f2bf(tile[r][c]);
    unsigned hi = f2bf(tile[r + 1][c]);
    *reinterpret_cast<unsigned*>(d + (size_t)(c0 + c) * R + (r0 + r)) = lo | (hi << 16);
  }
}

// ---------- router: logits, softmax, top-2, renorm, counts; also emits x in bf16 ----------
__global__ __launch_bounds__(256) void router_kernel(const float* __restrict__ x,
                                                     const float* __restrict__ Wr,
                                                     const float* __restrict__ br,
                                                     int* __restrict__ cnt,
                                                     int* __restrict__ tidx,
                                                     float* __restrict__ tw,
                                                     unsigned short* __restrict__ xb) {
  int lane = threadIdx.x & 63;
  int n = blockIdx.x * 4 + (threadIdx.x >> 6);
  const float* xr = x + (size_t)n * DIMD;
  unsigned short* xbr = xb + (size_t)n * DIMD;
  float acc[NEXP];
#pragma unroll
  for (int e = 0; e < NEXP; ++e) acc[e] = 0.f;
#pragma unroll
  for (int it = 0; it < DIMD / 64; ++it) {
    int d = lane + it * 64;
    float xv = xr[d];
    xbr[d] = f2bf(xv);
    const float* wr = Wr + (size_t)d * NEXP;
#pragma unroll
    for (int e = 0; e < NEXP; ++e) acc[e] += xv * wr[e];
  }
#pragma unroll
  for (int e = 0; e < NEXP; ++e) {
    float v = acc[e];
#pragma unroll
    for (int off = 32; off > 0; off >>= 1) v += __shfl_xor(v, off, 64);
    acc[e] = v + br[e];
  }
  if (lane == 0) {
    float m = acc[0];
    for (int e = 1; e < NEXP; ++e) m = fmaxf(m, acc[e]);
    float p[NEXP], s = 0.f;
    for (int e = 0; e < NEXP; ++e) { p[e] = expf(acc[e] - m); s += p[e]; }
    float inv = 1.f / s;
    for (int e = 0; e < NEXP; ++e) p[e] *= inv;
    int i0 = 0; float p0 = p[0];
    for (int e = 1; e < NEXP; ++e) if (p[e] > p0) { p0 = p[e]; i0 = e; }
    int i1 = (i0 == 0) ? 1 : 0; float p1 = p[i1];
    for (int e = 0; e < NEXP; ++e) if (e != i0 && p[e] > p1) { p1 = p[e]; i1 = e; }
    float t = expf(p1 - p0);
    float w0 = 1.f / (1.f + t);
    tidx[2 * n] = i0; tidx[2 * n + 1] = i1;
    tw[2 * n] = w0; tw[2 * n + 1] = t * w0;
    atomicAdd(&cnt[i0], 1);
    atomicAdd(&cnt[i1], 1);
  }
}

// ---------- offsets + lb_loss/load tail ----------
__global__ void finalize_kernel(const int* __restrict__ cnt, int* __restrict__ off,
                                int* __restrict__ cur, float* __restrict__ out_tail) {
  if (threadIdx.x == 0) {
    int o = 0;
    float lb = 0.f;
    for (int e = 0; e < NEXP; ++e) {
      off[e] = o; o += cnt[e];
      float l = (float)cnt[e] / (float)NASG;
      out_tail[1 + e] = l;
      float dd = l - 0.125f;
      lb += dd * dd;
      cur[e] = 0;
    }
    off[NEXP] = o;
    out_tail[0] = lb;
  }
}

// ---------- scatter assignment ids into per-expert lists ----------
__global__ __launch_bounds__(256) void scatter_kernel(const int* __restrict__ tidx,
                                                      const int* __restrict__ off,
                                                      int* __restrict__ cur,
                                                      int* __restrict__ list) {
  int a = blockIdx.x * 256 + threadIdx.x;
  if (a < NASG) {
    int e = tidx[a];
    int pos = off[e] + atomicAdd(&cur[e], 1);
    list[pos] = a;
  }
}

// ---------- GEMM1: H[offe+r][0..2048) = gelu(Xg[r] @ W1 + b1), m97 structure ----------
// 128x128 tile, BK=64, gload_lds w/ pre-swizzled source, XOR-swizzled LDS reads.
__global__ __launch_bounds__(256) void gemm1_kernel(
    const unsigned short* __restrict__ xb,
    const unsigned short* __restrict__ w1t,   // [E][2048][512]
    const float* __restrict__ b1,
    const int* __restrict__ off,
    const int* __restrict__ list,
    unsigned short* __restrict__ H) {
  int e = blockIdx.z;
  int offe = off[e];
  int cnt_e = off[e + 1] - offe;
  int m0 = blockIdx.y * 128;
  if (m0 >= cnt_e) return;
  int n0 = blockIdx.x * 128;

  __shared__ char ldsb[32768];       // A: [0,16K), B: [16K,32K)
  char* AsB = ldsb;
  char* BsB = ldsb + 16384;

  int tid = threadIdx.x, wv = tid >> 6, lane = tid & 63;
  int rsub = lane >> 3, sw = lane & 7;
  int ks = sw ^ rsub;                // pre-swizzled 16B k-slot (rule #21: inverse-swz source)

  const unsigned short* w1e = w1t + (size_t)e * HIDN * DIMD;
  const unsigned short* asrc[4];
  const unsigned short* bsrc[4];
#pragma unroll
  for (int i = 0; i < 4; ++i) {
    int r = wv * 32 + i * 8 + rsub;
    int rr = m0 + r;
    int tok = 0;
    if (rr < cnt_e) tok = list[offe + rr] >> 1;
    asrc[i] = xb + (size_t)tok * DIMD + ks * 8;
    bsrc[i] = w1e + (size_t)(n0 + r) * DIMD + ks * 8;
  }

  f32x4 zero = {0.f, 0.f, 0.f, 0.f};
  f32x4 acc[4][4];
#pragma unroll
  for (int m = 0; m < 4; ++m)
#pragma unroll
    for (int n = 0; n < 4; ++n) acc[m][n] = zero;

  int wave_m = wv >> 1, wave_n = wv & 1;
  int lane16 = lane & 15, kq = lane >> 4;
  int swzr = (lane16 & 7) << 4;

  for (int t = 0; t < DIMD / 64; ++t) {
    int k0 = t * 64;
#pragma unroll
    for (int i = 0; i < 4; ++i) {
      gl16(asrc[i] + k0, AsB + (wv * 32 + i * 8) * 128);
      gl16(bsrc[i] + k0, BsB + (wv * 32 + i * 8) * 128);
    }
    __syncthreads();                 // drains vmcnt (gload_lds) + barrier
#pragma unroll
    for (int kk = 0; kk < 2; ++kk) {
      bf16x8 af[4], bfr[4];
#pragma unroll
      for (int m = 0; m < 4; ++m)
        af[m] = *reinterpret_cast<const bf16x8*>(
            AsB + (((wave_m * 64 + m * 16 + lane16) * 128 + kk * 64 + kq * 16) ^ swzr));
#pragma unroll
      for (int n = 0; n < 4; ++n)
        bfr[n] = *reinterpret_cast<const bf16x8*>(
            BsB + (((wave_n * 64 + n * 16 + lane16) * 128 + kk * 64 + kq * 16) ^ swzr));
#pragma unroll
      for (int m = 0; m < 4; ++m)
#pragma unroll
        for (int n = 0; n < 4; ++n)
          acc[m][n] = __builtin_amdgcn_mfma_f32_16x16x32_bf16(af[m], bfr[n], acc[m][n], 0, 0, 0);
    }
    __syncthreads();
  }

  const float* b1e = b1 + e * HIDN;
#pragma unroll
  for (int n = 0; n < 4; ++n) {
    int col = n0 + wave_n * 64 + n * 16 + lane16;
    float bias = b1e[col];
#pragma unroll
    for (int m = 0; m < 4; ++m) {
#pragma unroll
      for (int q = 0; q < 4; ++q) {
        int r = m0 + wave_m * 64 + m * 16 + kq * 4 + q;
        if (r < cnt_e) {
          float v = acc[m][n][q] + bias;
          float g = 0.5f * v * (1.f + erff(v * 0.70710678118654752f));
          H[(size_t)(offe + r) * HIDN + col] = f2bf(g);
        }
      }
    }
  }
}

// ---------- GEMM2: Yw[a][col] = tw[a]*(H[offe+r] @ W2 + b2), m97 structure ----------
__global__ __launch_bounds__(256) void gemm2_kernel(
    const unsigned short* __restrict__ H,
    const unsigned short* __restrict__ w2t,   // [E][512][2048]
    const float* __restrict__ b2,
    const int* __restrict__ off,
    const int* __restrict__ list,
    const float* __restrict__ tw,
    float* __restrict__ Yw) {
  int e = blockIdx.z;
  int offe = off[e];
  int cnt_e = off[e + 1] - offe;
  int m0 = blockIdx.y * 128;
  if (m0 >= cnt_e) return;
  int n0 = blockIdx.x * 128;

  __shared__ char ldsb[32768];
  char* AsB = ldsb;
  char* BsB = ldsb + 16384;

  int tid = threadIdx.x, wv = tid >> 6, lane = tid & 63;
  int rsub = lane >> 3, sw = lane & 7;
  int ks = sw ^ rsub;

  const unsigned short* w2e = w2t + (size_t)e * DIMD * HIDN;
  const unsigned short* asrc[4];
  const unsigned short* bsrc[4];
#pragma unroll
  for (int i = 0; i < 4; ++i) {
    int r = wv * 32 + i * 8 + rsub;
    int rowa = offe + m0 + r;
    if (rowa > NASG - 1) rowa = NASG - 1;   // pad rows: clamp (values discarded)
    asrc[i] = H + (size_t)rowa * HIDN + ks * 8;
    bsrc[i] = w2e + (size_t)(n0 + r) * HIDN + ks * 8;
  }

  f32x4 zero = {0.f, 0.f, 0.f, 0.f};
  f32x4 acc[4][4];
#pragma unroll
  for (int m = 0; m < 4; ++m)
#pragma unroll
    for (int n = 0; n < 4; ++n) acc[m][n] = zero;

  int wave_m = wv >> 1, wave_n = wv & 1;
  int lane16 = lane & 15, kq = lane >> 4;
  int swzr = (lane16 & 7) << 4;

  for (int t = 0; t < HIDN / 64; ++t) {
    int k0 = t * 64;
#pragma unroll
    for (int i = 0; i < 4; ++i) {
      gl16(asrc[i] + k0, AsB + (wv * 32 + i * 8) * 128);
      gl16(bsrc[i] + k0, BsB + (wv * 32 + i * 8) * 128);
    }
    __syncthreads();
#pragma unroll
    for (int kk = 0; kk < 2; ++kk) {
      bf16x8 af[4], bfr[4];
#pragma unroll
      for (int m = 0; m < 4; ++m)
        af[m] = *reinterpret_cast<const bf16x8*>(
            AsB + (((wave_m * 64 + m * 16 + lane16) * 128 + kk * 64 + kq * 16) ^ swzr));
#pragma unroll
      for (int n = 0; n < 4; ++n)
        bfr[n] = *reinterpret_cast<const bf16x8*>(
            BsB + (((wave_n * 64 + n * 16 + lane16) * 128 + kk * 64 + kq * 16) ^ swzr));
#pragma unroll
      for (int m = 0; m < 4; ++m)
#pragma unroll
        for (int n = 0; n < 4; ++n)
          acc[m][n] = __builtin_amdgcn_mfma_f32_16x16x32_bf16(af[m], bfr[n], acc[m][n], 0, 0, 0);
    }
    __syncthreads();
  }

  const float* b2e = b2 + e * DIMD;
  float bias[4];
#pragma unroll
  for (int n = 0; n < 4; ++n) bias[n] = b2e[n0 + wave_n * 64 + n * 16 + lane16];
#pragma unroll
  for (int m = 0; m < 4; ++m) {
#pragma unroll
    for (int q = 0; q < 4; ++q) {
      int r = m0 + wave_m * 64 + m * 16 + kq * 4 + q;
      if (r < cnt_e) {
        int a = list[offe + r];
        float w = tw[a];
        float* yrow = Yw + (size_t)a * DIMD;
#pragma unroll
        for (int n = 0; n < 4; ++n) {
          int col = n0 + wave_n * 64 + n * 16 + lane16;
          yrow[col] = w * (acc[m][n][q] + bias[n]);
        }
      }
    }
  }
}

// ---------- combine: out[n] = Yw[2n] + Yw[2n+1] ----------
__global__ __launch_bounds__(256) void combine_kernel(const float* __restrict__ Yw,
                                                      float* __restrict__ out) {
  int i = (blockIdx.x * 256 + threadIdx.x) * 4;
  int n = i >> 9;
  int d = i & 511;
  float4 a = *reinterpret_cast<const float4*>(Yw + (size_t)(2 * n) * DIMD + d);
  float4 b = *reinterpret_cast<const float4*>(Yw + (size_t)(2 * n + 1) * DIMD + d);
  float4 o;
  o.x = a.x + b.x; o.y = a.y + b.y; o.z = a.z + b.z; o.w = a.w + b.w;
  *reinterpret_cast<float4*>(out + i) = o;
}

extern "C" void kernel_launch(void* const* d_in, const int* in_sizes, int n_in,
                              void* d_out, int out_size, void* d_ws, size_t ws_size,
                              hipStream_t stream) {
  const float* x  = (const float*)d_in[0];
  const float* Wr = (const float*)d_in[1];
  const float* br = (const float*)d_in[2];
  const float* W1 = (const float*)d_in[3];
  const float* b1 = (const float*)d_in[4];
  const float* W2 = (const float*)d_in[5];
  const float* b2 = (const float*)d_in[6];
  float* out = (float*)d_out;

  char* ws = (char*)d_ws;
  unsigned short* xb  = (unsigned short*)ws;  ws += (size_t)NTOK * DIMD * 2;
  unsigned short* w1t = (unsigned short*)ws;  ws += (size_t)NEXP * HIDN * DIMD * 2;
  unsigned short* w2t = (unsigned short*)ws;  ws += (size_t)NEXP * DIMD * HIDN * 2;
  unsigned short* H   = (unsigned short*)ws;  ws += (size_t)NASG * HIDN * 2;
  float* Yw = (float*)ws;                     ws += (size_t)NASG * DIMD * 4;
  float* tw = (float*)ws;                     ws += (size_t)NASG * 4;
  int* tidx = (int*)ws;                       ws += (size_t)NASG * 4;
  int* list = (int*)ws;                       ws += (size_t)NASG * 4;
  int* ctrl = (int*)ws;                       // cnt[8], cur[8], off[9]
  int* cnt = ctrl;
  int* cur = ctrl + 8;
  int* offp = ctrl + 16;

  hipMemsetAsync(ctrl, 0, 32 * sizeof(int), stream);
  transpose_w_kernel<<<dim3(HIDN / 64, DIMD / 64, NEXP), 256, 0, stream>>>(W1, w1t, DIMD, HIDN);
  transpose_w_kernel<<<dim3(DIMD / 64, HIDN / 64, NEXP), 256, 0, stream>>>(W2, w2t, HIDN, DIMD);
  router_kernel<<<NTOK / 4, 256, 0, stream>>>(x, Wr, br, cnt, tidx, tw, xb);
  finalize_kernel<<<1, 64, 0, stream>>>(cnt, offp, cur, out + (size_t)NTOK * DIMD);
  scatter_kernel<<<NASG / 256, 256, 0, stream>>>(tidx, offp, cur, list);
  gemm1_kernel<<<dim3(HIDN / 128, NASG / 128, NEXP), 256, 0, stream>>>(xb, w1t, b1, offp, list, H);
  gemm2_kernel<<<dim3(DIMD / 128, NASG / 128, NEXP), 256, 0, stream>>>(H, w2t, b2, offp, list, tw, Yw);
  combine_kernel<<<2048, 256, 0, stream>>>(Yw, out);
}

// Round 5
// 162.039 us; speedup vs baseline: 3.2027x; 1.7898x over previous
//
#include <hip/hip_runtime.h>
#include <hip/hip_bf16.h>

#define DIMD 512
#define NEXP 8
#define HIDN 2048
#define NTOK 4096
#define NASG 8192

typedef short bf16x8 __attribute__((ext_vector_type(8)));
typedef float f32x4 __attribute__((ext_vector_type(4)));

__device__ inline unsigned short f2bf(float f) {
  __hip_bfloat16 h = __float2bfloat16(f);
  return __builtin_bit_cast(unsigned short, h);
}

__device__ inline void gl16(const void* g, void* l) {
  __builtin_amdgcn_global_load_lds(
      (const __attribute__((address_space(1))) unsigned int*)g,
      (__attribute__((address_space(3))) unsigned int*)l, 16, 0, 0);
}

// ---------- W [E][R][C] fp32 -> WT [E][C][R] bf16 (tiled transpose) ----------
__global__ __launch_bounds__(256) void transpose_w_kernel(const float* __restrict__ src,
                                                          unsigned short* __restrict__ dst,
                                                          int R, int C) {
  __shared__ float tile[64][65];
  int e = blockIdx.z;
  int c0 = blockIdx.x * 64, r0 = blockIdx.y * 64;
  const float* s = src + (size_t)e * R * C;
  unsigned short* d = dst + (size_t)e * R * C;
  for (int i = threadIdx.x; i < 4096; i += 256) {
    int r = i >> 6, c = i & 63;
    tile[r][c] = s[(size_t)(r0 + r) * C + (c0 + c)];
  }
  __syncthreads();
  for (int i = threadIdx.x; i < 2048; i += 256) {
    int c = i >> 5;
    int r = (i & 31) * 2;
    unsigned lo = f2bf(tile[r][c]);
    unsigned hi = f2bf(tile[r + 1][c]);
    *reinterpret_cast<unsigned*>(d + (size_t)(c0 + c) * R + (r0 + r)) = lo | (hi << 16);
  }
}

// ---------- router: logits, softmax, top-2, renorm; emits x in bf16. NO atomics. ----------
__global__ __launch_bounds__(256) void router_kernel(const float* __restrict__ x,
                                                     const float* __restrict__ Wr,
                                                     const float* __restrict__ br,
                                                     int* __restrict__ tidx,
                                                     float* __restrict__ tw,
                                                     unsigned short* __restrict__ xb) {
  int lane = threadIdx.x & 63;
  int n = blockIdx.x * 4 + (threadIdx.x >> 6);
  const float* xr = x + (size_t)n * DIMD;
  unsigned short* xbr = xb + (size_t)n * DIMD;
  float acc[NEXP];
#pragma unroll
  for (int e = 0; e < NEXP; ++e) acc[e] = 0.f;
#pragma unroll
  for (int it = 0; it < 2; ++it) {
    int d0 = it * 256 + lane * 4;
    float4 xv = *reinterpret_cast<const float4*>(xr + d0);
    unsigned p0 = (unsigned)f2bf(xv.x) | ((unsigned)f2bf(xv.y) << 16);
    unsigned p1 = (unsigned)f2bf(xv.z) | ((unsigned)f2bf(xv.w) << 16);
    *reinterpret_cast<uint2*>(xbr + d0) = make_uint2(p0, p1);
    const float* wr = Wr + (size_t)d0 * NEXP;
#pragma unroll
    for (int j = 0; j < 4; ++j) {
      float xj = (&xv.x)[j];
#pragma unroll
      for (int e = 0; e < NEXP; ++e) acc[e] += xj * wr[j * NEXP + e];
    }
  }
#pragma unroll
  for (int e = 0; e < NEXP; ++e) {
    float v = acc[e];
#pragma unroll
    for (int off = 32; off > 0; off >>= 1) v += __shfl_xor(v, off, 64);
    acc[e] = v + br[e];
  }
  if (lane == 0) {
    float m = acc[0];
    for (int e = 1; e < NEXP; ++e) m = fmaxf(m, acc[e]);
    float p[NEXP], s = 0.f;
    for (int e = 0; e < NEXP; ++e) { p[e] = expf(acc[e] - m); s += p[e]; }
    float inv = 1.f / s;
    for (int e = 0; e < NEXP; ++e) p[e] *= inv;
    int i0 = 0; float p0 = p[0];
    for (int e = 1; e < NEXP; ++e) if (p[e] > p0) { p0 = p[e]; i0 = e; }
    int i1 = (i0 == 0) ? 1 : 0; float p1 = p[i1];
    for (int e = 0; e < NEXP; ++e) if (e != i0 && p[e] > p1) { p1 = p[e]; i1 = e; }
    // reference renormalizes by softmax over the top-2 *probabilities*
    float t = expf(p1 - p0);
    float w0 = 1.f / (1.f + t);
    tidx[2 * n] = i0; tidx[2 * n + 1] = i1;
    tw[2 * n] = w0; tw[2 * n + 1] = t * w0;
  }
}

// ---------- route_pack: counts + offsets + stable scatter + lb tail, single block ----------
// 1024 threads x 8 assignments each. No global atomics; deterministic.
__global__ __launch_bounds__(1024) void route_pack_kernel(const int* __restrict__ tidx,
                                                          int* __restrict__ off,
                                                          int* __restrict__ list,
                                                          float* __restrict__ out_tail) {
  int tid = threadIdx.x;
  int wv = tid >> 6, lane = tid & 63;

  int ids[8];
#pragma unroll
  for (int j = 0; j < 8; ++j) ids[j] = tidx[tid * 8 + j];

  int c[NEXP];
#pragma unroll
  for (int e = 0; e < NEXP; ++e) c[e] = 0;
#pragma unroll
  for (int j = 0; j < 8; ++j)
#pragma unroll
    for (int e = 0; e < NEXP; ++e) c[e] += (ids[j] == e) ? 1 : 0;

  // per-bin inclusive scan within wave
  int inc[NEXP];
#pragma unroll
  for (int e = 0; e < NEXP; ++e) {
    int v = c[e];
#pragma unroll
    for (int d = 1; d < 64; d <<= 1) {
      int t = __shfl_up(v, d, 64);
      if (lane >= d) v += t;
    }
    inc[e] = v;
  }

  __shared__ int wtot[NEXP][16];
  __shared__ int wbase[NEXP][16];
  __shared__ int ebase[NEXP];
  if (lane == 63) {
#pragma unroll
    for (int e = 0; e < NEXP; ++e) wtot[e][wv] = inc[e];
  }
  __syncthreads();
  if (tid == 0) {
    int o = 0;
    float lb = 0.f;
    for (int e = 0; e < NEXP; ++e) {
      int s = 0;
      for (int w = 0; w < 16; ++w) { wbase[e][w] = s; s += wtot[e][w]; }
      ebase[e] = o;
      off[e] = o;
      o += s;
      float l = (float)s / (float)NASG;
      out_tail[1 + e] = l;
      float dd = l - 0.125f;
      lb += dd * dd;
    }
    off[NEXP] = o;
    out_tail[0] = lb;
  }
  __syncthreads();

  int pos[NEXP];
#pragma unroll
  for (int e = 0; e < NEXP; ++e)
    pos[e] = ebase[e] + wbase[e][wv] + (inc[e] - c[e]);   // exclusive base

#pragma unroll
  for (int j = 0; j < 8; ++j) {
    int e = ids[j];
    int p = 0;
#pragma unroll
    for (int k = 0; k < NEXP; ++k)
      if (e == k) { p = pos[k]; pos[k] = p + 1; }   // constant-indexed regs (rule #20)
    list[p] = tid * 8 + j;
  }
}

// ---------- GEMM1: H[offe+r][0..2048) = gelu(Xg[r] @ W1 + b1), m97 structure ----------
__global__ __launch_bounds__(256) void gemm1_kernel(
    const unsigned short* __restrict__ xb,
    const unsigned short* __restrict__ w1t,   // [E][2048][512]
    const float* __restrict__ b1,
    const int* __restrict__ off,
    const int* __restrict__ list,
    unsigned short* __restrict__ H) {
  int e = blockIdx.z;
  int offe = off[e];
  int cnt_e = off[e + 1] - offe;
  int m0 = blockIdx.y * 128;
  if (m0 >= cnt_e) return;
  int n0 = blockIdx.x * 128;

  __shared__ char ldsb[32768];       // A: [0,16K), B: [16K,32K)
  char* AsB = ldsb;
  char* BsB = ldsb + 16384;

  int tid = threadIdx.x, wv = tid >> 6, lane = tid & 63;
  int rsub = lane >> 3, sw = lane & 7;
  int ks = sw ^ rsub;                // pre-swizzled 16B k-slot (rule #21)

  const unsigned short* w1e = w1t + (size_t)e * HIDN * DIMD;
  const unsigned short* asrc[4];
  const unsigned short* bsrc[4];
#pragma unroll
  for (int i = 0; i < 4; ++i) {
    int r = wv * 32 + i * 8 + rsub;
    int rr = m0 + r;
    int tok = 0;
    if (rr < cnt_e) tok = list[offe + rr] >> 1;
    asrc[i] = xb + (size_t)tok * DIMD + ks * 8;
    bsrc[i] = w1e + (size_t)(n0 + r) * DIMD + ks * 8;
  }

  f32x4 zero = {0.f, 0.f, 0.f, 0.f};
  f32x4 acc[4][4];
#pragma unroll
  for (int m = 0; m < 4; ++m)
#pragma unroll
    for (int n = 0; n < 4; ++n) acc[m][n] = zero;

  int wave_m = wv >> 1, wave_n = wv & 1;
  int lane16 = lane & 15, kq = lane >> 4;
  int swzr = (lane16 & 7) << 4;

  for (int t = 0; t < DIMD / 64; ++t) {
    int k0 = t * 64;
#pragma unroll
    for (int i = 0; i < 4; ++i) {
      gl16(asrc[i] + k0, AsB + (wv * 32 + i * 8) * 128);
      gl16(bsrc[i] + k0, BsB + (wv * 32 + i * 8) * 128);
    }
    __syncthreads();
#pragma unroll
    for (int kk = 0; kk < 2; ++kk) {
      bf16x8 af[4], bfr[4];
#pragma unroll
      for (int m = 0; m < 4; ++m)
        af[m] = *reinterpret_cast<const bf16x8*>(
            AsB + (((wave_m * 64 + m * 16 + lane16) * 128 + kk * 64 + kq * 16) ^ swzr));
#pragma unroll
      for (int n = 0; n < 4; ++n)
        bfr[n] = *reinterpret_cast<const bf16x8*>(
            BsB + (((wave_n * 64 + n * 16 + lane16) * 128 + kk * 64 + kq * 16) ^ swzr));
#pragma unroll
      for (int m = 0; m < 4; ++m)
#pragma unroll
        for (int n = 0; n < 4; ++n)
          acc[m][n] = __builtin_amdgcn_mfma_f32_16x16x32_bf16(af[m], bfr[n], acc[m][n], 0, 0, 0);
    }
    __syncthreads();
  }

  const float* b1e = b1 + e * HIDN;
#pragma unroll
  for (int n = 0; n < 4; ++n) {
    int col = n0 + wave_n * 64 + n * 16 + lane16;
    float bias = b1e[col];
#pragma unroll
    for (int m = 0; m < 4; ++m) {
#pragma unroll
      for (int q = 0; q < 4; ++q) {
        int r = m0 + wave_m * 64 + m * 16 + kq * 4 + q;
        if (r < cnt_e) {
          float v = acc[m][n][q] + bias;
          float g = 0.5f * v * (1.f + erff(v * 0.70710678118654752f));
          H[(size_t)(offe + r) * HIDN + col] = f2bf(g);
        }
      }
    }
  }
}

// ---------- GEMM2: Yw[a][col] = tw[a]*(H[offe+r] @ W2 + b2), m97 structure ----------
__global__ __launch_bounds__(256) void gemm2_kernel(
    const unsigned short* __restrict__ H,
    const unsigned short* __restrict__ w2t,   // [E][512][2048]
    const float* __restrict__ b2,
    const int* __restrict__ off,
    const int* __restrict__ list,
    const float* __restrict__ tw,
    float* __restrict__ Yw) {
  int e = blockIdx.z;
  int offe = off[e];
  int cnt_e = off[e + 1] - offe;
  int m0 = blockIdx.y * 128;
  if (m0 >= cnt_e) return;
  int n0 = blockIdx.x * 128;

  __shared__ char ldsb[32768];
  char* AsB = ldsb;
  char* BsB = ldsb + 16384;

  int tid = threadIdx.x, wv = tid >> 6, lane = tid & 63;
  int rsub = lane >> 3, sw = lane & 7;
  int ks = sw ^ rsub;

  const unsigned short* w2e = w2t + (size_t)e * DIMD * HIDN;
  const unsigned short* asrc[4];
  const unsigned short* bsrc[4];
#pragma unroll
  for (int i = 0; i < 4; ++i) {
    int r = wv * 32 + i * 8 + rsub;
    int rowa = offe + m0 + r;
    if (rowa > NASG - 1) rowa = NASG - 1;   // pad rows: clamp (values discarded)
    asrc[i] = H + (size_t)rowa * HIDN + ks * 8;
    bsrc[i] = w2e + (size_t)(n0 + r) * HIDN + ks * 8;
  }

  f32x4 zero = {0.f, 0.f, 0.f, 0.f};
  f32x4 acc[4][4];
#pragma unroll
  for (int m = 0; m < 4; ++m)
#pragma unroll
    for (int n = 0; n < 4; ++n) acc[m][n] = zero;

  int wave_m = wv >> 1, wave_n = wv & 1;
  int lane16 = lane & 15, kq = lane >> 4;
  int swzr = (lane16 & 7) << 4;

  for (int t = 0; t < HIDN / 64; ++t) {
    int k0 = t * 64;
#pragma unroll
    for (int i = 0; i < 4; ++i) {
      gl16(asrc[i] + k0, AsB + (wv * 32 + i * 8) * 128);
      gl16(bsrc[i] + k0, BsB + (wv * 32 + i * 8) * 128);
    }
    __syncthreads();
#pragma unroll
    for (int kk = 0; kk < 2; ++kk) {
      bf16x8 af[4], bfr[4];
#pragma unroll
      for (int m = 0; m < 4; ++m)
        af[m] = *reinterpret_cast<const bf16x8*>(
            AsB + (((wave_m * 64 + m * 16 + lane16) * 128 + kk * 64 + kq * 16) ^ swzr));
#pragma unroll
      for (int n = 0; n < 4; ++n)
        bfr[n] = *reinterpret_cast<const bf16x8*>(
            BsB + (((wave_n * 64 + n * 16 + lane16) * 128 + kk * 64 + kq * 16) ^ swzr));
#pragma unroll
      for (int m = 0; m < 4; ++m)
#pragma unroll
        for (int n = 0; n < 4; ++n)
          acc[m][n] = __builtin_amdgcn_mfma_f32_16x16x32_bf16(af[m], bfr[n], acc[m][n], 0, 0, 0);
    }
    __syncthreads();
  }

  const float* b2e = b2 + e * DIMD;
  float bias[4];
#pragma unroll
  for (int n = 0; n < 4; ++n) bias[n] = b2e[n0 + wave_n * 64 + n * 16 + lane16];
#pragma unroll
  for (int m = 0; m < 4; ++m) {
#pragma unroll
    for (int q = 0; q < 4; ++q) {
      int r = m0 + wave_m * 64 + m * 16 + kq * 4 + q;
      if (r < cnt_e) {
        int a = list[offe + r];
        float w = tw[a];
        float* yrow = Yw + (size_t)a * DIMD;
#pragma unroll
        for (int n = 0; n < 4; ++n) {
          int col = n0 + wave_n * 64 + n * 16 + lane16;
          yrow[col] = w * (acc[m][n][q] + bias[n]);
        }
      }
    }
  }
}

// ---------- combine: out[n] = Yw[2n] + Yw[2n+1] ----------
__global__ __launch_bounds__(256) void combine_kernel(const float* __restrict__ Yw,
                                                      float* __restrict__ out) {
  int i = (blockIdx.x * 256 + threadIdx.x) * 4;
  int n = i >> 9;
  int d = i & 511;
  float4 a = *reinterpret_cast<const float4*>(Yw + (size_t)(2 * n) * DIMD + d);
  float4 b = *reinterpret_cast<const float4*>(Yw + (size_t)(2 * n + 1) * DIMD + d);
  float4 o;
  o.x = a.x + b.x; o.y = a.y + b.y; o.z = a.z + b.z; o.w = a.w + b.w;
  *reinterpret_cast<float4*>(out + i) = o;
}

extern "C" void kernel_launch(void* const* d_in, const int* in_sizes, int n_in,
                              void* d_out, int out_size, void* d_ws, size_t ws_size,
                              hipStream_t stream) {
  const float* x  = (const float*)d_in[0];
  const float* Wr = (const float*)d_in[1];
  const float* br = (const float*)d_in[2];
  const float* W1 = (const float*)d_in[3];
  const float* b1 = (const float*)d_in[4];
  const float* W2 = (const float*)d_in[5];
  const float* b2 = (const float*)d_in[6];
  float* out = (float*)d_out;

  char* ws = (char*)d_ws;
  unsigned short* xb  = (unsigned short*)ws;  ws += (size_t)NTOK * DIMD * 2;
  unsigned short* w1t = (unsigned short*)ws;  ws += (size_t)NEXP * HIDN * DIMD * 2;
  unsigned short* w2t = (unsigned short*)ws;  ws += (size_t)NEXP * DIMD * HIDN * 2;
  unsigned short* H   = (unsigned short*)ws;  ws += (size_t)NASG * HIDN * 2;
  float* Yw = (float*)ws;                     ws += (size_t)NASG * DIMD * 4;
  float* tw = (float*)ws;                     ws += (size_t)NASG * 4;
  int* tidx = (int*)ws;                       ws += (size_t)NASG * 4;
  int* list = (int*)ws;                       ws += (size_t)NASG * 4;
  int* offp = (int*)ws;                       // off[9]

  transpose_w_kernel<<<dim3(HIDN / 64, DIMD / 64, NEXP), 256, 0, stream>>>(W1, w1t, DIMD, HIDN);
  transpose_w_kernel<<<dim3(DIMD / 64, HIDN / 64, NEXP), 256, 0, stream>>>(W2, w2t, HIDN, DIMD);
  router_kernel<<<NTOK / 4, 256, 0, stream>>>(x, Wr, br, tidx, tw, xb);
  route_pack_kernel<<<1, 1024, 0, stream>>>(tidx, offp, list, out + (size_t)NTOK * DIMD);
  gemm1_kernel<<<dim3(HIDN / 128, NASG / 128, NEXP), 256, 0, stream>>>(xb, w1t, b1, offp, list, H);
  gemm2_kernel<<<dim3(DIMD / 128, NASG / 128, NEXP), 256, 0, stream>>>(H, w2t, b2, offp, list, tw, Yw);
  combine_kernel<<<2048, 256, 0, stream>>>(Yw, out);
}

// Round 6
// 124.694 us; speedup vs baseline: 4.1618x; 1.2995x over previous
//
#include <hip/hip_runtime.h>
#include <hip/hip_bf16.h>

#define DIMD 512
#define NEXP 8
#define HIDN 2048
#define NTOK 4096
#define NASG 8192

typedef short bf16x8 __attribute__((ext_vector_type(8)));
typedef float f32x4 __attribute__((ext_vector_type(4)));

__device__ inline unsigned short f2bf(float f) {
  __hip_bfloat16 h = __float2bfloat16(f);
  return __builtin_bit_cast(unsigned short, h);
}

__device__ inline void gl16(const void* g, void* l) {
  __builtin_amdgcn_global_load_lds(
      (const __attribute__((address_space(1))) unsigned int*)g,
      (__attribute__((address_space(3))) unsigned int*)l, 16, 0, 0);
}

// ---------- both W transposes in one launch: [E][R][C] fp32 -> [E][C][R] bf16 ----------
__global__ __launch_bounds__(256) void transpose_both_kernel(
    const float* __restrict__ W1, const float* __restrict__ W2,
    unsigned short* __restrict__ w1t, unsigned short* __restrict__ w2t) {
  __shared__ float tile[64][65];
  int z = blockIdx.z;
  int e = z & 7;
  const float* src; unsigned short* dst; int R, C, r0, c0;
  if (z < 8) { src = W1; dst = w1t; R = DIMD; C = HIDN; c0 = blockIdx.x * 64; r0 = blockIdx.y * 64; }
  else       { src = W2; dst = w2t; R = HIDN; C = DIMD; r0 = blockIdx.x * 64; c0 = blockIdx.y * 64; }
  const float* s = src + (size_t)e * R * C;
  unsigned short* d = dst + (size_t)e * R * C;
  for (int i = threadIdx.x; i < 4096; i += 256) {
    int r = i >> 6, c = i & 63;
    tile[r][c] = s[(size_t)(r0 + r) * C + (c0 + c)];
  }
  __syncthreads();
  for (int i = threadIdx.x; i < 2048; i += 256) {
    int c = i >> 5;
    int r = (i & 31) * 2;
    unsigned lo = f2bf(tile[r][c]);
    unsigned hi = f2bf(tile[r + 1][c]);
    *reinterpret_cast<unsigned*>(d + (size_t)(c0 + c) * R + (r0 + r)) = lo | (hi << 16);
  }
}

// ---------- router: logits, softmax, top-2, renorm; emits x in bf16. NO atomics. ----------
__global__ __launch_bounds__(256) void router_kernel(const float* __restrict__ x,
                                                     const float* __restrict__ Wr,
                                                     const float* __restrict__ br,
                                                     int* __restrict__ tidx,
                                                     float* __restrict__ tw,
                                                     unsigned short* __restrict__ xb) {
  int lane = threadIdx.x & 63;
  int n = blockIdx.x * 4 + (threadIdx.x >> 6);
  const float* xr = x + (size_t)n * DIMD;
  unsigned short* xbr = xb + (size_t)n * DIMD;
  float acc[NEXP];
#pragma unroll
  for (int e = 0; e < NEXP; ++e) acc[e] = 0.f;
#pragma unroll
  for (int it = 0; it < 2; ++it) {
    int d0 = it * 256 + lane * 4;
    float4 xv = *reinterpret_cast<const float4*>(xr + d0);
    unsigned p0 = (unsigned)f2bf(xv.x) | ((unsigned)f2bf(xv.y) << 16);
    unsigned p1 = (unsigned)f2bf(xv.z) | ((unsigned)f2bf(xv.w) << 16);
    *reinterpret_cast<uint2*>(xbr + d0) = make_uint2(p0, p1);
    const float* wr = Wr + (size_t)d0 * NEXP;
#pragma unroll
    for (int j = 0; j < 4; ++j) {
      float xj = (&xv.x)[j];
#pragma unroll
      for (int e = 0; e < NEXP; ++e) acc[e] += xj * wr[j * NEXP + e];
    }
  }
#pragma unroll
  for (int e = 0; e < NEXP; ++e) {
    float v = acc[e];
#pragma unroll
    for (int off = 32; off > 0; off >>= 1) v += __shfl_xor(v, off, 64);
    acc[e] = v + br[e];
  }
  if (lane == 0) {
    float m = acc[0];
    for (int e = 1; e < NEXP; ++e) m = fmaxf(m, acc[e]);
    float p[NEXP], s = 0.f;
    for (int e = 0; e < NEXP; ++e) { p[e] = expf(acc[e] - m); s += p[e]; }
    float inv = 1.f / s;
    for (int e = 0; e < NEXP; ++e) p[e] *= inv;
    int i0 = 0; float p0 = p[0];
    for (int e = 1; e < NEXP; ++e) if (p[e] > p0) { p0 = p[e]; i0 = e; }
    int i1 = (i0 == 0) ? 1 : 0; float p1 = p[i1];
    for (int e = 0; e < NEXP; ++e) if (e != i0 && p[e] > p1) { p1 = p[e]; i1 = e; }
    // reference renormalizes by softmax over the top-2 *probabilities*
    float t = expf(p1 - p0);
    float w0 = 1.f / (1.f + t);
    tidx[2 * n] = i0; tidx[2 * n + 1] = i1;
    tw[2 * n] = w0; tw[2 * n + 1] = t * w0;
  }
}

// ---------- route_pack: counts + offsets + stable scatter + lb tail, single block ----------
__global__ __launch_bounds__(1024) void route_pack_kernel(const int* __restrict__ tidx,
                                                          int* __restrict__ off,
                                                          int* __restrict__ list,
                                                          float* __restrict__ out_tail) {
  int tid = threadIdx.x;
  int wv = tid >> 6, lane = tid & 63;

  int ids[8];
#pragma unroll
  for (int j = 0; j < 8; ++j) ids[j] = tidx[tid * 8 + j];

  int c[NEXP];
#pragma unroll
  for (int e = 0; e < NEXP; ++e) c[e] = 0;
#pragma unroll
  for (int j = 0; j < 8; ++j)
#pragma unroll
    for (int e = 0; e < NEXP; ++e) c[e] += (ids[j] == e) ? 1 : 0;

  int inc[NEXP];
#pragma unroll
  for (int e = 0; e < NEXP; ++e) {
    int v = c[e];
#pragma unroll
    for (int d = 1; d < 64; d <<= 1) {
      int t = __shfl_up(v, d, 64);
      if (lane >= d) v += t;
    }
    inc[e] = v;
  }

  __shared__ int wtot[NEXP][16];
  __shared__ int wbase[NEXP][16];
  __shared__ int ebase[NEXP];
  if (lane == 63) {
#pragma unroll
    for (int e = 0; e < NEXP; ++e) wtot[e][wv] = inc[e];
  }
  __syncthreads();
  if (tid == 0) {
    int o = 0;
    float lb = 0.f;
    for (int e = 0; e < NEXP; ++e) {
      int s = 0;
      for (int w = 0; w < 16; ++w) { wbase[e][w] = s; s += wtot[e][w]; }
      ebase[e] = o;
      off[e] = o;
      o += s;
      float l = (float)s / (float)NASG;
      out_tail[1 + e] = l;
      float dd = l - 0.125f;
      lb += dd * dd;
    }
    off[NEXP] = o;
    out_tail[0] = lb;
  }
  __syncthreads();

  int pos[NEXP];
#pragma unroll
  for (int e = 0; e < NEXP; ++e)
    pos[e] = ebase[e] + wbase[e][wv] + (inc[e] - c[e]);

#pragma unroll
  for (int j = 0; j < 8; ++j) {
    int e = ids[j];
    int p = 0;
#pragma unroll
    for (int k = 0; k < NEXP; ++k)
      if (e == k) { p = pos[k]; pos[k] = p + 1; }
    list[p] = tid * 8 + j;
  }
}

// ---------- GEMM1: H = gelu(Xg @ W1 + b1); dbuf 2-phase, LDS-staged H store ----------
__global__ __launch_bounds__(256) void gemm1_kernel(
    const unsigned short* __restrict__ xb,
    const unsigned short* __restrict__ w1t,   // [E][2048][512]
    const float* __restrict__ b1,
    const int* __restrict__ off,
    const int* __restrict__ list,
    unsigned short* __restrict__ H) {
  int e = blockIdx.z;
  int offe = off[e];
  int cnt_e = off[e + 1] - offe;
  int m0 = blockIdx.y * 128;
  if (m0 >= cnt_e) return;
  int n0 = blockIdx.x * 128;

  __shared__ char ldsb[65536];       // 2 x (A 16K | B 16K)

  int tid = threadIdx.x, wv = tid >> 6, lane = tid & 63;
  int rsub = lane >> 3, sw = lane & 7;
  int ks = sw ^ rsub;                // pre-swizzled 16B k-slot (rule #21)

  const unsigned short* w1e = w1t + (size_t)e * HIDN * DIMD;
  const unsigned short* asrc[4];
  const unsigned short* bsrc[4];
#pragma unroll
  for (int i = 0; i < 4; ++i) {
    int r = wv * 32 + i * 8 + rsub;
    int rr = m0 + r;
    int tok = 0;
    if (rr < cnt_e) tok = list[offe + rr] >> 1;
    asrc[i] = xb + (size_t)tok * DIMD + ks * 8;
    bsrc[i] = w1e + (size_t)(n0 + r) * DIMD + ks * 8;
  }

  f32x4 zero = {0.f, 0.f, 0.f, 0.f};
  f32x4 acc[4][4];
#pragma unroll
  for (int m = 0; m < 4; ++m)
#pragma unroll
    for (int n = 0; n < 4; ++n) acc[m][n] = zero;

  int wave_m = wv >> 1, wave_n = wv & 1;
  int lane16 = lane & 15, kq = lane >> 4;
  int swzr = (lane16 & 7) << 4;

  const int T = DIMD / 64;
  // prologue: stage tile 0 into buf 0
#pragma unroll
  for (int i = 0; i < 4; ++i) {
    gl16(asrc[i], ldsb + (wv * 32 + i * 8) * 128);
    gl16(bsrc[i], ldsb + 16384 + (wv * 32 + i * 8) * 128);
  }
  __syncthreads();

  for (int t = 0; t < T; ++t) {
    char* cb = ldsb + (t & 1) * 32768;
    if (t + 1 < T) {
      char* nb = ldsb + ((t + 1) & 1) * 32768;
      int k0 = (t + 1) * 64;
#pragma unroll
      for (int i = 0; i < 4; ++i) {
        gl16(asrc[i] + k0, nb + (wv * 32 + i * 8) * 128);
        gl16(bsrc[i] + k0, nb + 16384 + (wv * 32 + i * 8) * 128);
      }
    }
#pragma unroll
    for (int kk = 0; kk < 2; ++kk) {
      bf16x8 af[4], bfr[4];
#pragma unroll
      for (int m = 0; m < 4; ++m)
        af[m] = *reinterpret_cast<const bf16x8*>(
            cb + (((wave_m * 64 + m * 16 + lane16) * 128 + kk * 64 + kq * 16) ^ swzr));
#pragma unroll
      for (int n = 0; n < 4; ++n)
        bfr[n] = *reinterpret_cast<const bf16x8*>(
            cb + 16384 + (((wave_n * 64 + n * 16 + lane16) * 128 + kk * 64 + kq * 16) ^ swzr));
#pragma unroll
      for (int m = 0; m < 4; ++m)
#pragma unroll
        for (int n = 0; n < 4; ++n)
          acc[m][n] = __builtin_amdgcn_mfma_f32_16x16x32_bf16(af[m], bfr[n], acc[m][n], 0, 0, 0);
    }
    __syncthreads();   // drains stage loads; protects both buffers (barrier-after-compute)
  }

  // epilogue: gelu -> bf16 C-tile in LDS (stride 136), then coalesced uint4 store
  unsigned short* Ct = (unsigned short*)ldsb;
  const float* b1e = b1 + e * HIDN;
#pragma unroll
  for (int n = 0; n < 4; ++n) {
    int cl = wave_n * 64 + n * 16 + lane16;
    float bias = b1e[n0 + cl];
#pragma unroll
    for (int m = 0; m < 4; ++m) {
#pragma unroll
      for (int q = 0; q < 4; ++q) {
        int rl = wave_m * 64 + m * 16 + kq * 4 + q;
        float v = acc[m][n][q] + bias;
        float g = 0.5f * v * (1.f + erff(v * 0.70710678118654752f));
        Ct[rl * 136 + cl] = f2bf(g);
      }
    }
  }
  __syncthreads();
  for (int u = tid; u < 2048; u += 256) {
    int rl = u >> 4, c8 = (u & 15) * 8;
    int r = m0 + rl;
    if (r < cnt_e) {
      uint4 v = *reinterpret_cast<const uint4*>(Ct + rl * 136 + c8);
      *reinterpret_cast<uint4*>(H + (size_t)(offe + r) * HIDN + n0 + c8) = v;
    }
  }
}

// ---------- GEMM2: Yw[a] = tw[a]*(H @ W2 + b2); dbuf 2-phase ----------
__global__ __launch_bounds__(256) void gemm2_kernel(
    const unsigned short* __restrict__ H,
    const unsigned short* __restrict__ w2t,   // [E][512][2048]
    const float* __restrict__ b2,
    const int* __restrict__ off,
    const int* __restrict__ list,
    const float* __restrict__ tw,
    float* __restrict__ Yw) {
  int e = blockIdx.z;
  int offe = off[e];
  int cnt_e = off[e + 1] - offe;
  int m0 = blockIdx.y * 128;
  if (m0 >= cnt_e) return;
  int n0 = blockIdx.x * 128;

  __shared__ char ldsb[65536];

  int tid = threadIdx.x, wv = tid >> 6, lane = tid & 63;
  int rsub = lane >> 3, sw = lane & 7;
  int ks = sw ^ rsub;

  const unsigned short* w2e = w2t + (size_t)e * DIMD * HIDN;
  const unsigned short* asrc[4];
  const unsigned short* bsrc[4];
#pragma unroll
  for (int i = 0; i < 4; ++i) {
    int r = wv * 32 + i * 8 + rsub;
    int rowa = offe + m0 + r;
    if (rowa > NASG - 1) rowa = NASG - 1;   // pad rows: clamp (values discarded)
    asrc[i] = H + (size_t)rowa * HIDN + ks * 8;
    bsrc[i] = w2e + (size_t)(n0 + r) * HIDN + ks * 8;
  }

  f32x4 zero = {0.f, 0.f, 0.f, 0.f};
  f32x4 acc[4][4];
#pragma unroll
  for (int m = 0; m < 4; ++m)
#pragma unroll
    for (int n = 0; n < 4; ++n) acc[m][n] = zero;

  int wave_m = wv >> 1, wave_n = wv & 1;
  int lane16 = lane & 15, kq = lane >> 4;
  int swzr = (lane16 & 7) << 4;

  const int T = HIDN / 64;
#pragma unroll
  for (int i = 0; i < 4; ++i) {
    gl16(asrc[i], ldsb + (wv * 32 + i * 8) * 128);
    gl16(bsrc[i], ldsb + 16384 + (wv * 32 + i * 8) * 128);
  }
  __syncthreads();

  for (int t = 0; t < T; ++t) {
    char* cb = ldsb + (t & 1) * 32768;
    if (t + 1 < T) {
      char* nb = ldsb + ((t + 1) & 1) * 32768;
      int k0 = (t + 1) * 64;
#pragma unroll
      for (int i = 0; i < 4; ++i) {
        gl16(asrc[i] + k0, nb + (wv * 32 + i * 8) * 128);
        gl16(bsrc[i] + k0, nb + 16384 + (wv * 32 + i * 8) * 128);
      }
    }
#pragma unroll
    for (int kk = 0; kk < 2; ++kk) {
      bf16x8 af[4], bfr[4];
#pragma unroll
      for (int m = 0; m < 4; ++m)
        af[m] = *reinterpret_cast<const bf16x8*>(
            cb + (((wave_m * 64 + m * 16 + lane16) * 128 + kk * 64 + kq * 16) ^ swzr));
#pragma unroll
      for (int n = 0; n < 4; ++n)
        bfr[n] = *reinterpret_cast<const bf16x8*>(
            cb + 16384 + (((wave_n * 64 + n * 16 + lane16) * 128 + kk * 64 + kq * 16) ^ swzr));
#pragma unroll
      for (int m = 0; m < 4; ++m)
#pragma unroll
        for (int n = 0; n < 4; ++n)
          acc[m][n] = __builtin_amdgcn_mfma_f32_16x16x32_bf16(af[m], bfr[n], acc[m][n], 0, 0, 0);
    }
    __syncthreads();
  }

  const float* b2e = b2 + e * DIMD;
  float bias[4];
#pragma unroll
  for (int n = 0; n < 4; ++n) bias[n] = b2e[n0 + wave_n * 64 + n * 16 + lane16];
#pragma unroll
  for (int m = 0; m < 4; ++m) {
#pragma unroll
    for (int q = 0; q < 4; ++q) {
      int r = m0 + wave_m * 64 + m * 16 + kq * 4 + q;
      if (r < cnt_e) {
        int a = list[offe + r];
        float w = tw[a];
        float* yrow = Yw + (size_t)a * DIMD;
#pragma unroll
        for (int n = 0; n < 4; ++n) {
          int col = n0 + wave_n * 64 + n * 16 + lane16;
          yrow[col] = w * (acc[m][n][q] + bias[n]);
        }
      }
    }
  }
}

// ---------- combine: out[n] = Yw[2n] + Yw[2n+1] ----------
__global__ __launch_bounds__(256) void combine_kernel(const float* __restrict__ Yw,
                                                      float* __restrict__ out) {
  int i = (blockIdx.x * 256 + threadIdx.x) * 4;
  int n = i >> 9;
  int d = i & 511;
  float4 a = *reinterpret_cast<const float4*>(Yw + (size_t)(2 * n) * DIMD + d);
  float4 b = *reinterpret_cast<const float4*>(Yw + (size_t)(2 * n + 1) * DIMD + d);
  float4 o;
  o.x = a.x + b.x; o.y = a.y + b.y; o.z = a.z + b.z; o.w = a.w + b.w;
  *reinterpret_cast<float4*>(out + i) = o;
}

extern "C" void kernel_launch(void* const* d_in, const int* in_sizes, int n_in,
                              void* d_out, int out_size, void* d_ws, size_t ws_size,
                              hipStream_t stream) {
  const float* x  = (const float*)d_in[0];
  const float* Wr = (const float*)d_in[1];
  const float* br = (const float*)d_in[2];
  const float* W1 = (const float*)d_in[3];
  const float* b1 = (const float*)d_in[4];
  const float* W2 = (const float*)d_in[5];
  const float* b2 = (const float*)d_in[6];
  float* out = (float*)d_out;

  char* ws = (char*)d_ws;
  unsigned short* xb  = (unsigned short*)ws;  ws += (size_t)NTOK * DIMD * 2;
  unsigned short* w1t = (unsigned short*)ws;  ws += (size_t)NEXP * HIDN * DIMD * 2;
  unsigned short* w2t = (unsigned short*)ws;  ws += (size_t)NEXP * DIMD * HIDN * 2;
  unsigned short* H   = (unsigned short*)ws;  ws += (size_t)NASG * HIDN * 2;
  float* Yw = (float*)ws;                     ws += (size_t)NASG * DIMD * 4;
  float* tw = (float*)ws;                     ws += (size_t)NASG * 4;
  int* tidx = (int*)ws;                       ws += (size_t)NASG * 4;
  int* list = (int*)ws;                       ws += (size_t)NASG * 4;
  int* offp = (int*)ws;                       // off[9]

  transpose_both_kernel<<<dim3(32, 8, 16), 256, 0, stream>>>(W1, W2, w1t, w2t);
  router_kernel<<<NTOK / 4, 256, 0, stream>>>(x, Wr, br, tidx, tw, xb);
  route_pack_kernel<<<1, 1024, 0, stream>>>(tidx, offp, list, out + (size_t)NTOK * DIMD);
  gemm1_kernel<<<dim3(HIDN / 128, NASG / 128, NEXP), 256, 0, stream>>>(xb, w1t, b1, offp, list, H);
  gemm2_kernel<<<dim3(DIMD / 128, NASG / 128, NEXP), 256, 0, stream>>>(H, w2t, b2, offp, list, tw, Yw);
  combine_kernel<<<2048, 256, 0, stream>>>(Yw, out);
}

// Round 7
// 118.529 us; speedup vs baseline: 4.3783x; 1.0520x over previous
//
#include <hip/hip_runtime.h>
#include <hip/hip_bf16.h>

#define DIMD 512
#define NEXP 8
#define HIDN 2048
#define NTOK 4096
#define NASG 8192

typedef short bf16x8 __attribute__((ext_vector_type(8)));
typedef float f32x4 __attribute__((ext_vector_type(4)));

__device__ inline unsigned short f2bf(float f) {
  __hip_bfloat16 h = __float2bfloat16(f);
  return __builtin_bit_cast(unsigned short, h);
}

__device__ inline void gl16(const void* g, void* l) {
  __builtin_amdgcn_global_load_lds(
      (const __attribute__((address_space(1))) unsigned int*)g,
      (__attribute__((address_space(3))) unsigned int*)l, 16, 0, 0);
}

// ---------- both W transposes in one launch: [E][R][C] fp32 -> [E][C][R] bf16 ----------
__global__ __launch_bounds__(256) void transpose_both_kernel(
    const float* __restrict__ W1, const float* __restrict__ W2,
    unsigned short* __restrict__ w1t, unsigned short* __restrict__ w2t) {
  __shared__ float tile[64][65];
  int z = blockIdx.z;
  int e = z & 7;
  const float* src; unsigned short* dst; int R, C, r0, c0;
  if (z < 8) { src = W1; dst = w1t; R = DIMD; C = HIDN; c0 = blockIdx.x * 64; r0 = blockIdx.y * 64; }
  else       { src = W2; dst = w2t; R = HIDN; C = DIMD; r0 = blockIdx.x * 64; c0 = blockIdx.y * 64; }
  const float* s = src + (size_t)e * R * C;
  unsigned short* d = dst + (size_t)e * R * C;
  for (int i = threadIdx.x; i < 4096; i += 256) {
    int r = i >> 6, c = i & 63;
    tile[r][c] = s[(size_t)(r0 + r) * C + (c0 + c)];
  }
  __syncthreads();
  for (int i = threadIdx.x; i < 2048; i += 256) {
    int c = i >> 5;
    int r = (i & 31) * 2;
    unsigned lo = f2bf(tile[r][c]);
    unsigned hi = f2bf(tile[r + 1][c]);
    *reinterpret_cast<unsigned*>(d + (size_t)(c0 + c) * R + (r0 + r)) = lo | (hi << 16);
  }
}

// ---------- router: logits, softmax, top-2, renorm; emits x in bf16. NO atomics. ----------
__global__ __launch_bounds__(256) void router_kernel(const float* __restrict__ x,
                                                     const float* __restrict__ Wr,
                                                     const float* __restrict__ br,
                                                     int* __restrict__ tidx,
                                                     float* __restrict__ tw,
                                                     unsigned short* __restrict__ xb) {
  int lane = threadIdx.x & 63;
  int n = blockIdx.x * 4 + (threadIdx.x >> 6);
  const float* xr = x + (size_t)n * DIMD;
  unsigned short* xbr = xb + (size_t)n * DIMD;
  float acc[NEXP];
#pragma unroll
  for (int e = 0; e < NEXP; ++e) acc[e] = 0.f;
#pragma unroll
  for (int it = 0; it < 2; ++it) {
    int d0 = it * 256 + lane * 4;
    float4 xv = *reinterpret_cast<const float4*>(xr + d0);
    unsigned p0 = (unsigned)f2bf(xv.x) | ((unsigned)f2bf(xv.y) << 16);
    unsigned p1 = (unsigned)f2bf(xv.z) | ((unsigned)f2bf(xv.w) << 16);
    *reinterpret_cast<uint2*>(xbr + d0) = make_uint2(p0, p1);
    const float* wr = Wr + (size_t)d0 * NEXP;
#pragma unroll
    for (int j = 0; j < 4; ++j) {
      float xj = (&xv.x)[j];
#pragma unroll
      for (int e = 0; e < NEXP; ++e) acc[e] += xj * wr[j * NEXP + e];
    }
  }
#pragma unroll
  for (int e = 0; e < NEXP; ++e) {
    float v = acc[e];
#pragma unroll
    for (int off = 32; off > 0; off >>= 1) v += __shfl_xor(v, off, 64);
    acc[e] = v + br[e];
  }
  if (lane == 0) {
    float m = acc[0];
    for (int e = 1; e < NEXP; ++e) m = fmaxf(m, acc[e]);
    float p[NEXP], s = 0.f;
    for (int e = 0; e < NEXP; ++e) { p[e] = expf(acc[e] - m); s += p[e]; }
    float inv = 1.f / s;
    for (int e = 0; e < NEXP; ++e) p[e] *= inv;
    int i0 = 0; float p0 = p[0];
    for (int e = 1; e < NEXP; ++e) if (p[e] > p0) { p0 = p[e]; i0 = e; }
    int i1 = (i0 == 0) ? 1 : 0; float p1 = p[i1];
    for (int e = 0; e < NEXP; ++e) if (e != i0 && p[e] > p1) { p1 = p[e]; i1 = e; }
    // reference renormalizes by softmax over the top-2 *probabilities*
    float t = expf(p1 - p0);
    float w0 = 1.f / (1.f + t);
    tidx[2 * n] = i0; tidx[2 * n + 1] = i1;
    tw[2 * n] = w0; tw[2 * n + 1] = t * w0;
  }
}

// ---------- route_pack: counts + offsets + stable scatter + lb tail, single block ----------
__global__ __launch_bounds__(1024) void route_pack_kernel(const int* __restrict__ tidx,
                                                          int* __restrict__ off,
                                                          int* __restrict__ list,
                                                          float* __restrict__ out_tail) {
  int tid = threadIdx.x;
  int wv = tid >> 6, lane = tid & 63;

  int ids[8];
#pragma unroll
  for (int j = 0; j < 8; ++j) ids[j] = tidx[tid * 8 + j];

  int c[NEXP];
#pragma unroll
  for (int e = 0; e < NEXP; ++e) c[e] = 0;
#pragma unroll
  for (int j = 0; j < 8; ++j)
#pragma unroll
    for (int e = 0; e < NEXP; ++e) c[e] += (ids[j] == e) ? 1 : 0;

  int inc[NEXP];
#pragma unroll
  for (int e = 0; e < NEXP; ++e) {
    int v = c[e];
#pragma unroll
    for (int d = 1; d < 64; d <<= 1) {
      int t = __shfl_up(v, d, 64);
      if (lane >= d) v += t;
    }
    inc[e] = v;
  }

  __shared__ int wtot[NEXP][16];
  __shared__ int wbase[NEXP][16];
  __shared__ int ebase[NEXP];
  if (lane == 63) {
#pragma unroll
    for (int e = 0; e < NEXP; ++e) wtot[e][wv] = inc[e];
  }
  __syncthreads();
  if (tid == 0) {
    int o = 0;
    float lb = 0.f;
    for (int e = 0; e < NEXP; ++e) {
      int s = 0;
      for (int w = 0; w < 16; ++w) { wbase[e][w] = s; s += wtot[e][w]; }
      ebase[e] = o;
      off[e] = o;
      o += s;
      float l = (float)s / (float)NASG;
      out_tail[1 + e] = l;
      float dd = l - 0.125f;
      lb += dd * dd;
    }
    off[NEXP] = o;
    out_tail[0] = lb;
  }
  __syncthreads();

  int pos[NEXP];
#pragma unroll
  for (int e = 0; e < NEXP; ++e)
    pos[e] = ebase[e] + wbase[e][wv] + (inc[e] - c[e]);

#pragma unroll
  for (int j = 0; j < 8; ++j) {
    int e = ids[j];
    int p = 0;
#pragma unroll
    for (int k = 0; k < NEXP; ++k)
      if (e == k) { p = pos[k]; pos[k] = p + 1; }
    list[p] = tid * 8 + j;
  }
}

// ===== BK=32 tile helpers: row-pair packed LDS, 2-way-free swizzle =====
// LDS tile: 128 rows x 32 k (64B/row), packed as 64 row-pairs x 128B.
// byte(r, kq) = (r>>1)*128 + (((kq + (r&1)*4) ^ ((r>>1)&7)) << 4)
// Staged linearly by gl16 (lane*16) from pre-swizzled global sources:
//   lane -> rp=lane>>3, s=lane&7; holds row R0+rp*2+((s^rp)>>2), kchunk=(s^rp)&3.

// ---------- GEMM1: H = gelu(Xg @ W1 + b1); dbuf BK=32, 4 blocks/CU ----------
__global__ __launch_bounds__(256) void gemm1_kernel(
    const unsigned short* __restrict__ xb,
    const unsigned short* __restrict__ w1t,   // [E][2048][512]
    const float* __restrict__ b1,
    const int* __restrict__ off,
    const int* __restrict__ list,
    unsigned short* __restrict__ H) {
  int e = blockIdx.x;                        // linear%8 == e -> expert pinned to one XCD
  int offe = off[e];
  int cnt_e = off[e + 1] - offe;
  int n0 = blockIdx.y * 128;
  int m0 = blockIdx.z * 128;
  if (m0 >= cnt_e) return;

  __shared__ char ldsb[36864];   // 2 x (A 8K | B 8K) = 32K; epilogue uses 34816

  int tid = threadIdx.x, wv = tid >> 6, lane = tid & 63;
  int rp = lane >> 3, sl = lane & 7;
  int sx = sl ^ rp;
  int rowadd = rp * 2 + (sx >> 2);           // row within 16-row chunk
  int kq = sx & 3;                           // 8-elem k-chunk

  const unsigned short* w1e = w1t + (size_t)e * HIDN * DIMD;
  const unsigned short* asrc[2];
  const unsigned short* bsrc[2];
#pragma unroll
  for (int i = 0; i < 2; ++i) {
    int r = wv * 32 + i * 16 + rowadd;
    int rr = m0 + r;
    int tok = 0;
    if (rr < cnt_e) tok = list[offe + rr] >> 1;
    asrc[i] = xb + (size_t)tok * DIMD + kq * 8;
    bsrc[i] = w1e + (size_t)(n0 + r) * DIMD + kq * 8;
  }
  int dstA0 = wv * 2048;                     // (wv*32)*64
  int dstA1 = wv * 2048 + 1024;

  f32x4 zero = {0.f, 0.f, 0.f, 0.f};
  f32x4 acc[4][4];
#pragma unroll
  for (int m = 0; m < 4; ++m)
#pragma unroll
    for (int n = 0; n < 4; ++n) acc[m][n] = zero;

  int wave_m = wv >> 1, wave_n = wv & 1;
  int lane16 = lane & 15, kq4 = lane >> 4;
  // read byte offsets (within 8K tile) for A row blocks m and B row blocks n
  int ra[4], rb[4];
#pragma unroll
  for (int m = 0; m < 4; ++m) {
    int r = wave_m * 64 + m * 16 + lane16;
    ra[m] = (r >> 1) * 128 + ((((kq4 + (r & 1) * 4)) ^ ((r >> 1) & 7)) << 4);
    int rn = wave_n * 64 + m * 16 + lane16;
    rb[m] = (rn >> 1) * 128 + ((((kq4 + (rn & 1) * 4)) ^ ((rn >> 1) & 7)) << 4);
  }

  const int T = DIMD / 32;   // 16 steps
  // prologue: stage tile 0 into buf 0
  gl16(asrc[0], ldsb + dstA0);
  gl16(asrc[1], ldsb + dstA1);
  gl16(bsrc[0], ldsb + 8192 + dstA0);
  gl16(bsrc[1], ldsb + 8192 + dstA1);
  __syncthreads();

  for (int t = 0; t < T; ++t) {
    char* cb = ldsb + (t & 1) * 16384;
    if (t + 1 < T) {
      char* nb = ldsb + ((t + 1) & 1) * 16384;
      int k0 = (t + 1) * 32;
      gl16(asrc[0] + k0, nb + dstA0);
      gl16(asrc[1] + k0, nb + dstA1);
      gl16(bsrc[0] + k0, nb + 8192 + dstA0);
      gl16(bsrc[1] + k0, nb + 8192 + dstA1);
    }
    bf16x8 af[4], bfr[4];
#pragma unroll
    for (int m = 0; m < 4; ++m) af[m] = *reinterpret_cast<const bf16x8*>(cb + ra[m]);
#pragma unroll
    for (int n = 0; n < 4; ++n) bfr[n] = *reinterpret_cast<const bf16x8*>(cb + 8192 + rb[n]);
#pragma unroll
    for (int m = 0; m < 4; ++m)
#pragma unroll
      for (int n = 0; n < 4; ++n)
        acc[m][n] = __builtin_amdgcn_mfma_f32_16x16x32_bf16(af[m], bfr[n], acc[m][n], 0, 0, 0);
    __syncthreads();   // drains stage loads; protects both buffers
  }

  // epilogue: gelu -> bf16 C-tile in LDS (stride 136 shorts), coalesced uint4 store
  unsigned short* Ct = (unsigned short*)ldsb;
  const float* b1e = b1 + e * HIDN;
#pragma unroll
  for (int n = 0; n < 4; ++n) {
    int cl = wave_n * 64 + n * 16 + lane16;
    float bias = b1e[n0 + cl];
#pragma unroll
    for (int m = 0; m < 4; ++m) {
#pragma unroll
      for (int q = 0; q < 4; ++q) {
        int rl = wave_m * 64 + m * 16 + kq4 * 4 + q;
        float v = acc[m][n][q] + bias;
        float g = 0.5f * v * (1.f + erff(v * 0.70710678118654752f));
        Ct[rl * 136 + cl] = f2bf(g);
      }
    }
  }
  __syncthreads();
  for (int u = tid; u < 2048; u += 256) {
    int rl = u >> 4, c8 = (u & 15) * 8;
    int r = m0 + rl;
    if (r < cnt_e) {
      uint4 v = *reinterpret_cast<const uint4*>(Ct + rl * 136 + c8);
      *reinterpret_cast<uint4*>(H + (size_t)(offe + r) * HIDN + n0 + c8) = v;
    }
  }
}

// ---------- GEMM2: Yw[a] = tw[a]*(H @ W2 + b2); dbuf BK=32 ----------
__global__ __launch_bounds__(256) void gemm2_kernel(
    const unsigned short* __restrict__ H,
    const unsigned short* __restrict__ w2t,   // [E][512][2048]
    const float* __restrict__ b2,
    const int* __restrict__ off,
    const int* __restrict__ list,
    const float* __restrict__ tw,
    float* __restrict__ Yw) {
  int e = blockIdx.x;
  int offe = off[e];
  int cnt_e = off[e + 1] - offe;
  int n0 = blockIdx.y * 128;
  int m0 = blockIdx.z * 128;
  if (m0 >= cnt_e) return;

  __shared__ char ldsb[32768];

  int tid = threadIdx.x, wv = tid >> 6, lane = tid & 63;
  int rp = lane >> 3, sl = lane & 7;
  int sx = sl ^ rp;
  int rowadd = rp * 2 + (sx >> 2);
  int kq = sx & 3;

  const unsigned short* w2e = w2t + (size_t)e * DIMD * HIDN;
  const unsigned short* asrc[2];
  const unsigned short* bsrc[2];
#pragma unroll
  for (int i = 0; i < 2; ++i) {
    int r = wv * 32 + i * 16 + rowadd;
    int rowa = offe + m0 + r;
    if (rowa > NASG - 1) rowa = NASG - 1;    // pad rows: clamp (values discarded)
    asrc[i] = H + (size_t)rowa * HIDN + kq * 8;
    bsrc[i] = w2e + (size_t)(n0 + r) * HIDN + kq * 8;
  }
  int dstA0 = wv * 2048;
  int dstA1 = wv * 2048 + 1024;

  f32x4 zero = {0.f, 0.f, 0.f, 0.f};
  f32x4 acc[4][4];
#pragma unroll
  for (int m = 0; m < 4; ++m)
#pragma unroll
    for (int n = 0; n < 4; ++n) acc[m][n] = zero;

  int wave_m = wv >> 1, wave_n = wv & 1;
  int lane16 = lane & 15, kq4 = lane >> 4;
  int ra[4], rb[4];
#pragma unroll
  for (int m = 0; m < 4; ++m) {
    int r = wave_m * 64 + m * 16 + lane16;
    ra[m] = (r >> 1) * 128 + ((((kq4 + (r & 1) * 4)) ^ ((r >> 1) & 7)) << 4);
    int rn = wave_n * 64 + m * 16 + lane16;
    rb[m] = (rn >> 1) * 128 + ((((kq4 + (rn & 1) * 4)) ^ ((rn >> 1) & 7)) << 4);
  }

  const int T = HIDN / 32;   // 64 steps
  gl16(asrc[0], ldsb + dstA0);
  gl16(asrc[1], ldsb + dstA1);
  gl16(bsrc[0], ldsb + 8192 + dstA0);
  gl16(bsrc[1], ldsb + 8192 + dstA1);
  __syncthreads();

  for (int t = 0; t < T; ++t) {
    char* cb = ldsb + (t & 1) * 16384;
    if (t + 1 < T) {
      char* nb = ldsb + ((t + 1) & 1) * 16384;
      int k0 = (t + 1) * 32;
      gl16(asrc[0] + k0, nb + dstA0);
      gl16(asrc[1] + k0, nb + dstA1);
      gl16(bsrc[0] + k0, nb + 8192 + dstA0);
      gl16(bsrc[1] + k0, nb + 8192 + dstA1);
    }
    bf16x8 af[4], bfr[4];
#pragma unroll
    for (int m = 0; m < 4; ++m) af[m] = *reinterpret_cast<const bf16x8*>(cb + ra[m]);
#pragma unroll
    for (int n = 0; n < 4; ++n) bfr[n] = *reinterpret_cast<const bf16x8*>(cb + 8192 + rb[n]);
#pragma unroll
    for (int m = 0; m < 4; ++m)
#pragma unroll
      for (int n = 0; n < 4; ++n)
        acc[m][n] = __builtin_amdgcn_mfma_f32_16x16x32_bf16(af[m], bfr[n], acc[m][n], 0, 0, 0);
    __syncthreads();
  }

  const float* b2e = b2 + e * DIMD;
  float bias[4];
#pragma unroll
  for (int n = 0; n < 4; ++n) bias[n] = b2e[n0 + wave_n * 64 + n * 16 + lane16];
#pragma unroll
  for (int m = 0; m < 4; ++m) {
#pragma unroll
    for (int q = 0; q < 4; ++q) {
      int r = m0 + wave_m * 64 + m * 16 + kq4 * 4 + q;
      if (r < cnt_e) {
        int a = list[offe + r];
        float w = tw[a];
        float* yrow = Yw + (size_t)a * DIMD;
#pragma unroll
        for (int n = 0; n < 4; ++n) {
          int col = n0 + wave_n * 64 + n * 16 + lane16;
          yrow[col] = w * (acc[m][n][q] + bias[n]);
        }
      }
    }
  }
}

// ---------- combine: out[n] = Yw[2n] + Yw[2n+1] ----------
__global__ __launch_bounds__(256) void combine_kernel(const float* __restrict__ Yw,
                                                      float* __restrict__ out) {
  int i = (blockIdx.x * 256 + threadIdx.x) * 4;
  int n = i >> 9;
  int d = i & 511;
  float4 a = *reinterpret_cast<const float4*>(Yw + (size_t)(2 * n) * DIMD + d);
  float4 b = *reinterpret_cast<const float4*>(Yw + (size_t)(2 * n + 1) * DIMD + d);
  float4 o;
  o.x = a.x + b.x; o.y = a.y + b.y; o.z = a.z + b.z; o.w = a.w + b.w;
  *reinterpret_cast<float4*>(out + i) = o;
}

extern "C" void kernel_launch(void* const* d_in, const int* in_sizes, int n_in,
                              void* d_out, int out_size, void* d_ws, size_t ws_size,
                              hipStream_t stream) {
  const float* x  = (const float*)d_in[0];
  const float* Wr = (const float*)d_in[1];
  const float* br = (const float*)d_in[2];
  const float* W1 = (const float*)d_in[3];
  const float* b1 = (const float*)d_in[4];
  const float* W2 = (const float*)d_in[5];
  const float* b2 = (const float*)d_in[6];
  float* out = (float*)d_out;

  char* ws = (char*)d_ws;
  unsigned short* xb  = (unsigned short*)ws;  ws += (size_t)NTOK * DIMD * 2;
  unsigned short* w1t = (unsigned short*)ws;  ws += (size_t)NEXP * HIDN * DIMD * 2;
  unsigned short* w2t = (unsigned short*)ws;  ws += (size_t)NEXP * DIMD * HIDN * 2;
  unsigned short* H   = (unsigned short*)ws;  ws += (size_t)NASG * HIDN * 2;
  float* Yw = (float*)ws;                     ws += (size_t)NASG * DIMD * 4;
  float* tw = (float*)ws;                     ws += (size_t)NASG * 4;
  int* tidx = (int*)ws;                       ws += (size_t)NASG * 4;
  int* list = (int*)ws;                       ws += (size_t)NASG * 4;
  int* offp = (int*)ws;                       // off[9]

  transpose_both_kernel<<<dim3(32, 8, 16), 256, 0, stream>>>(W1, W2, w1t, w2t);
  router_kernel<<<NTOK / 4, 256, 0, stream>>>(x, Wr, br, tidx, tw, xb);
  route_pack_kernel<<<1, 1024, 0, stream>>>(tidx, offp, list, out + (size_t)NTOK * DIMD);
  // expert = blockIdx.x -> grid-linear %8 == expert -> XCD-pinned weight panels
  gemm1_kernel<<<dim3(NEXP, HIDN / 128, NASG / 128), 256, 0, stream>>>(xb, w1t, b1, offp, list, H);
  gemm2_kernel<<<dim3(NEXP, DIMD / 128, NASG / 128), 256, 0, stream>>>(H, w2t, b2, offp, list, tw, Yw);
  combine_kernel<<<2048, 256, 0, stream>>>(Yw, out);
}

// Round 8
// 118.263 us; speedup vs baseline: 4.3882x; 1.0023x over previous
//
#include <hip/hip_runtime.h>
#include <hip/hip_bf16.h>

#define DIMD 512
#define NEXP 8
#define HIDN 2048
#define NTOK 4096
#define NASG 8192

typedef short bf16x8 __attribute__((ext_vector_type(8)));
typedef float f32x4 __attribute__((ext_vector_type(4)));

__device__ inline unsigned short f2bf(float f) {
  __hip_bfloat16 h = __float2bfloat16(f);
  return __builtin_bit_cast(unsigned short, h);
}

__device__ inline void gl16(const void* g, void* l) {
  __builtin_amdgcn_global_load_lds(
      (const __attribute__((address_space(1))) unsigned int*)g,
      (__attribute__((address_space(3))) unsigned int*)l, 16, 0, 0);
}

// Counted-vmcnt barrier discipline (T4): wait only the OLDER stage's 4 loads.
// sched_barrier(0) per rule #18 (pin ds_reads/MFMAs to their phase).
#define PIPE_WAIT4_BAR() do { \
  asm volatile("s_waitcnt vmcnt(4)" ::: "memory"); \
  __builtin_amdgcn_s_barrier(); \
  __builtin_amdgcn_sched_barrier(0); } while (0)
#define PIPE_WAIT0_BAR() do { \
  asm volatile("s_waitcnt vmcnt(0)" ::: "memory"); \
  __builtin_amdgcn_s_barrier(); \
  __builtin_amdgcn_sched_barrier(0); } while (0)
#define PIPE_POST_BAR() do { \
  asm volatile("" ::: "memory"); \
  __builtin_amdgcn_sched_barrier(0); \
  __builtin_amdgcn_s_barrier(); } while (0)

// ---------- both W transposes in one launch: [E][R][C] fp32 -> [E][C][R] bf16 ----------
__global__ __launch_bounds__(256) void transpose_both_kernel(
    const float* __restrict__ W1, const float* __restrict__ W2,
    unsigned short* __restrict__ w1t, unsigned short* __restrict__ w2t) {
  __shared__ float tile[64][65];
  int z = blockIdx.z;
  int e = z & 7;
  const float* src; unsigned short* dst; int R, C, r0, c0;
  if (z < 8) { src = W1; dst = w1t; R = DIMD; C = HIDN; c0 = blockIdx.x * 64; r0 = blockIdx.y * 64; }
  else       { src = W2; dst = w2t; R = HIDN; C = DIMD; r0 = blockIdx.x * 64; c0 = blockIdx.y * 64; }
  const float* s = src + (size_t)e * R * C;
  unsigned short* d = dst + (size_t)e * R * C;
  for (int i = threadIdx.x; i < 4096; i += 256) {
    int r = i >> 6, c = i & 63;
    tile[r][c] = s[(size_t)(r0 + r) * C + (c0 + c)];
  }
  __syncthreads();
  for (int i = threadIdx.x; i < 2048; i += 256) {
    int c = i >> 5;
    int r = (i & 31) * 2;
    unsigned lo = f2bf(tile[r][c]);
    unsigned hi = f2bf(tile[r + 1][c]);
    *reinterpret_cast<unsigned*>(d + (size_t)(c0 + c) * R + (r0 + r)) = lo | (hi << 16);
  }
}

// ---------- router: logits, softmax, top-2, renorm; emits x in bf16. NO atomics. ----------
__global__ __launch_bounds__(256) void router_kernel(const float* __restrict__ x,
                                                     const float* __restrict__ Wr,
                                                     const float* __restrict__ br,
                                                     int* __restrict__ tidx,
                                                     float* __restrict__ tw,
                                                     unsigned short* __restrict__ xb) {
  int lane = threadIdx.x & 63;
  int n = blockIdx.x * 4 + (threadIdx.x >> 6);
  const float* xr = x + (size_t)n * DIMD;
  unsigned short* xbr = xb + (size_t)n * DIMD;
  float acc[NEXP];
#pragma unroll
  for (int e = 0; e < NEXP; ++e) acc[e] = 0.f;
#pragma unroll
  for (int it = 0; it < 2; ++it) {
    int d0 = it * 256 + lane * 4;
    float4 xv = *reinterpret_cast<const float4*>(xr + d0);
    unsigned p0 = (unsigned)f2bf(xv.x) | ((unsigned)f2bf(xv.y) << 16);
    unsigned p1 = (unsigned)f2bf(xv.z) | ((unsigned)f2bf(xv.w) << 16);
    *reinterpret_cast<uint2*>(xbr + d0) = make_uint2(p0, p1);
    const float* wr = Wr + (size_t)d0 * NEXP;
#pragma unroll
    for (int j = 0; j < 4; ++j) {
      float xj = (&xv.x)[j];
#pragma unroll
      for (int e = 0; e < NEXP; ++e) acc[e] += xj * wr[j * NEXP + e];
    }
  }
#pragma unroll
  for (int e = 0; e < NEXP; ++e) {
    float v = acc[e];
#pragma unroll
    for (int off = 32; off > 0; off >>= 1) v += __shfl_xor(v, off, 64);
    acc[e] = v + br[e];
  }
  if (lane == 0) {
    float m = acc[0];
    for (int e = 1; e < NEXP; ++e) m = fmaxf(m, acc[e]);
    float p[NEXP], s = 0.f;
    for (int e = 0; e < NEXP; ++e) { p[e] = expf(acc[e] - m); s += p[e]; }
    float inv = 1.f / s;
    for (int e = 0; e < NEXP; ++e) p[e] *= inv;
    int i0 = 0; float p0 = p[0];
    for (int e = 1; e < NEXP; ++e) if (p[e] > p0) { p0 = p[e]; i0 = e; }
    int i1 = (i0 == 0) ? 1 : 0; float p1 = p[i1];
    for (int e = 0; e < NEXP; ++e) if (e != i0 && p[e] > p1) { p1 = p[e]; i1 = e; }
    // reference renormalizes by softmax over the top-2 *probabilities*
    float t = expf(p1 - p0);
    float w0 = 1.f / (1.f + t);
    tidx[2 * n] = i0; tidx[2 * n + 1] = i1;
    tw[2 * n] = w0; tw[2 * n + 1] = t * w0;
  }
}

// ---------- route_pack: counts + offsets + stable scatter + lb tail, single block ----------
__global__ __launch_bounds__(1024) void route_pack_kernel(const int* __restrict__ tidx,
                                                          int* __restrict__ off,
                                                          int* __restrict__ list,
                                                          float* __restrict__ out_tail) {
  int tid = threadIdx.x;
  int wv = tid >> 6, lane = tid & 63;

  int ids[8];
#pragma unroll
  for (int j = 0; j < 8; ++j) ids[j] = tidx[tid * 8 + j];

  int c[NEXP];
#pragma unroll
  for (int e = 0; e < NEXP; ++e) c[e] = 0;
#pragma unroll
  for (int j = 0; j < 8; ++j)
#pragma unroll
    for (int e = 0; e < NEXP; ++e) c[e] += (ids[j] == e) ? 1 : 0;

  int inc[NEXP];
#pragma unroll
  for (int e = 0; e < NEXP; ++e) {
    int v = c[e];
#pragma unroll
    for (int d = 1; d < 64; d <<= 1) {
      int t = __shfl_up(v, d, 64);
      if (lane >= d) v += t;
    }
    inc[e] = v;
  }

  __shared__ int wtot[NEXP][16];
  __shared__ int wbase[NEXP][16];
  __shared__ int ebase[NEXP];
  if (lane == 63) {
#pragma unroll
    for (int e = 0; e < NEXP; ++e) wtot[e][wv] = inc[e];
  }
  __syncthreads();
  if (tid == 0) {
    int o = 0;
    float lb = 0.f;
    for (int e = 0; e < NEXP; ++e) {
      int s = 0;
      for (int w = 0; w < 16; ++w) { wbase[e][w] = s; s += wtot[e][w]; }
      ebase[e] = o;
      off[e] = o;
      o += s;
      float l = (float)s / (float)NASG;
      out_tail[1 + e] = l;
      float dd = l - 0.125f;
      lb += dd * dd;
    }
    off[NEXP] = o;
    out_tail[0] = lb;
  }
  __syncthreads();

  int pos[NEXP];
#pragma unroll
  for (int e = 0; e < NEXP; ++e)
    pos[e] = ebase[e] + wbase[e][wv] + (inc[e] - c[e]);

#pragma unroll
  for (int j = 0; j < 8; ++j) {
    int e = ids[j];
    int p = 0;
#pragma unroll
    for (int k = 0; k < NEXP; ++k)
      if (e == k) { p = pos[k]; pos[k] = p + 1; }
    list[p] = tid * 8 + j;
  }
}

// ===== BK=32 tile helpers: row-pair packed LDS, 2-way-free swizzle =====
// LDS tile: 128 rows x 32 k (64B/row), packed as 64 row-pairs x 128B.
// byte(r, kq) = (r>>1)*128 + (((kq + (r&1)*4) ^ ((r>>1)&7)) << 4)
// Staged linearly by gl16 (lane*16) from pre-swizzled global sources.

// ---------- GEMM1: H = gelu(Xg @ W1 + b1); counted-vmcnt dbuf BK=32 ----------
__global__ __launch_bounds__(256) void gemm1_kernel(
    const unsigned short* __restrict__ xb,
    const unsigned short* __restrict__ w1t,   // [E][2048][512]
    const float* __restrict__ b1,
    const int* __restrict__ off,
    const int* __restrict__ list,
    unsigned short* __restrict__ H) {
  int e = blockIdx.x;                        // linear%8 == e -> expert pinned to one XCD
  int offe = off[e];
  int cnt_e = off[e + 1] - offe;
  int n0 = blockIdx.y * 128;
  int m0 = blockIdx.z * 128;
  if (m0 >= cnt_e) return;

  __shared__ char ldsb[36864];   // 2 x (A 8K | B 8K) = 32K; epilogue uses 34816

  int tid = threadIdx.x, wv = tid >> 6, lane = tid & 63;
  int rp = lane >> 3, sl = lane & 7;
  int sx = sl ^ rp;
  int rowadd = rp * 2 + (sx >> 2);
  int kq = sx & 3;

  const unsigned short* w1e = w1t + (size_t)e * HIDN * DIMD;
  const unsigned short* asrc[2];
  const unsigned short* bsrc[2];
#pragma unroll
  for (int i = 0; i < 2; ++i) {
    int r = wv * 32 + i * 16 + rowadd;
    int rr = m0 + r;
    int tok = 0;
    if (rr < cnt_e) tok = list[offe + rr] >> 1;
    asrc[i] = xb + (size_t)tok * DIMD + kq * 8;
    bsrc[i] = w1e + (size_t)(n0 + r) * DIMD + kq * 8;
  }
  int dstA0 = wv * 2048;
  int dstA1 = wv * 2048 + 1024;

  f32x4 zero = {0.f, 0.f, 0.f, 0.f};
  f32x4 acc[4][4];
#pragma unroll
  for (int m = 0; m < 4; ++m)
#pragma unroll
    for (int n = 0; n < 4; ++n) acc[m][n] = zero;

  int wave_m = wv >> 1, wave_n = wv & 1;
  int lane16 = lane & 15, kq4 = lane >> 4;
  int ra[4], rb[4];
#pragma unroll
  for (int m = 0; m < 4; ++m) {
    int r = wave_m * 64 + m * 16 + lane16;
    ra[m] = (r >> 1) * 128 + ((((kq4 + (r & 1) * 4)) ^ ((r >> 1) & 7)) << 4);
    int rn = wave_n * 64 + m * 16 + lane16;
    rb[m] = (rn >> 1) * 128 + ((((kq4 + (rn & 1) * 4)) ^ ((rn >> 1) & 7)) << 4);
  }

  auto stage = [&](char* nb, int k0) {
    gl16(asrc[0] + k0, nb + dstA0);
    gl16(asrc[1] + k0, nb + dstA1);
    gl16(bsrc[0] + k0, nb + 8192 + dstA0);
    gl16(bsrc[1] + k0, nb + 8192 + dstA1);
  };
  auto compute = [&](const char* cb) {
    bf16x8 af[4], bfr[4];
#pragma unroll
    for (int m = 0; m < 4; ++m) af[m] = *reinterpret_cast<const bf16x8*>(cb + ra[m]);
#pragma unroll
    for (int n = 0; n < 4; ++n) bfr[n] = *reinterpret_cast<const bf16x8*>(cb + 8192 + rb[n]);
#pragma unroll
    for (int m = 0; m < 4; ++m)
#pragma unroll
      for (int n = 0; n < 4; ++n)
        acc[m][n] = __builtin_amdgcn_mfma_f32_16x16x32_bf16(af[m], bfr[n], acc[m][n], 0, 0, 0);
  };

  const int T = DIMD / 32;   // 16 steps
  stage(ldsb, 0);
  stage(ldsb + 16384, 32);
  for (int t = 0; t < T - 2; ++t) {
    char* cb = ldsb + (t & 1) * 16384;
    PIPE_WAIT4_BAR();          // tile t ready; tile t+1 stays in flight
    compute(cb);
    PIPE_POST_BAR();           // all waves done reading buf[t&1]
    stage(cb, (t + 2) * 32);   // re-stage same buffer with tile t+2
  }
  PIPE_WAIT4_BAR();
  compute(ldsb + ((T - 2) & 1) * 16384);
  PIPE_POST_BAR();
  PIPE_WAIT0_BAR();
  compute(ldsb + ((T - 1) & 1) * 16384);
  PIPE_POST_BAR();             // vmcnt==0 per wave; LDS reuse below is safe

  // epilogue: gelu -> bf16 C-tile in LDS (stride 136 shorts), coalesced uint4 store
  unsigned short* Ct = (unsigned short*)ldsb;
  const float* b1e = b1 + e * HIDN;
#pragma unroll
  for (int n = 0; n < 4; ++n) {
    int cl = wave_n * 64 + n * 16 + lane16;
    float bias = b1e[n0 + cl];
#pragma unroll
    for (int m = 0; m < 4; ++m) {
#pragma unroll
      for (int q = 0; q < 4; ++q) {
        int rl = wave_m * 64 + m * 16 + kq4 * 4 + q;
        float v = acc[m][n][q] + bias;
        float g = 0.5f * v * (1.f + erff(v * 0.70710678118654752f));
        Ct[rl * 136 + cl] = f2bf(g);
      }
    }
  }
  __syncthreads();
  for (int u = tid; u < 2048; u += 256) {
    int rl = u >> 4, c8 = (u & 15) * 8;
    int r = m0 + rl;
    if (r < cnt_e) {
      uint4 v = *reinterpret_cast<const uint4*>(Ct + rl * 136 + c8);
      *reinterpret_cast<uint4*>(H + (size_t)(offe + r) * HIDN + n0 + c8) = v;
    }
  }
}

// ---------- GEMM2: Yw[a] = tw[a]*(H @ W2 + b2); counted-vmcnt dbuf BK=32 ----------
__global__ __launch_bounds__(256) void gemm2_kernel(
    const unsigned short* __restrict__ H,
    const unsigned short* __restrict__ w2t,   // [E][512][2048]
    const float* __restrict__ b2,
    const int* __restrict__ off,
    const int* __restrict__ list,
    const float* __restrict__ tw,
    float* __restrict__ Yw) {
  int e = blockIdx.x;
  int offe = off[e];
  int cnt_e = off[e + 1] - offe;
  int n0 = blockIdx.y * 128;
  int m0 = blockIdx.z * 128;
  if (m0 >= cnt_e) return;

  __shared__ char ldsb[32768];

  int tid = threadIdx.x, wv = tid >> 6, lane = tid & 63;
  int rp = lane >> 3, sl = lane & 7;
  int sx = sl ^ rp;
  int rowadd = rp * 2 + (sx >> 2);
  int kq = sx & 3;

  const unsigned short* w2e = w2t + (size_t)e * DIMD * HIDN;
  const unsigned short* asrc[2];
  const unsigned short* bsrc[2];
#pragma unroll
  for (int i = 0; i < 2; ++i) {
    int r = wv * 32 + i * 16 + rowadd;
    int rowa = offe + m0 + r;
    if (rowa > NASG - 1) rowa = NASG - 1;    // pad rows: clamp (values discarded)
    asrc[i] = H + (size_t)rowa * HIDN + kq * 8;
    bsrc[i] = w2e + (size_t)(n0 + r) * HIDN + kq * 8;
  }
  int dstA0 = wv * 2048;
  int dstA1 = wv * 2048 + 1024;

  f32x4 zero = {0.f, 0.f, 0.f, 0.f};
  f32x4 acc[4][4];
#pragma unroll
  for (int m = 0; m < 4; ++m)
#pragma unroll
    for (int n = 0; n < 4; ++n) acc[m][n] = zero;

  int wave_m = wv >> 1, wave_n = wv & 1;
  int lane16 = lane & 15, kq4 = lane >> 4;
  int ra[4], rb[4];
#pragma unroll
  for (int m = 0; m < 4; ++m) {
    int r = wave_m * 64 + m * 16 + lane16;
    ra[m] = (r >> 1) * 128 + ((((kq4 + (r & 1) * 4)) ^ ((r >> 1) & 7)) << 4);
    int rn = wave_n * 64 + m * 16 + lane16;
    rb[m] = (rn >> 1) * 128 + ((((kq4 + (rn & 1) * 4)) ^ ((rn >> 1) & 7)) << 4);
  }

  auto stage = [&](char* nb, int k0) {
    gl16(asrc[0] + k0, nb + dstA0);
    gl16(asrc[1] + k0, nb + dstA1);
    gl16(bsrc[0] + k0, nb + 8192 + dstA0);
    gl16(bsrc[1] + k0, nb + 8192 + dstA1);
  };
  auto compute = [&](const char* cb) {
    bf16x8 af[4], bfr[4];
#pragma unroll
    for (int m = 0; m < 4; ++m) af[m] = *reinterpret_cast<const bf16x8*>(cb + ra[m]);
#pragma unroll
    for (int n = 0; n < 4; ++n) bfr[n] = *reinterpret_cast<const bf16x8*>(cb + 8192 + rb[n]);
#pragma unroll
    for (int m = 0; m < 4; ++m)
#pragma unroll
      for (int n = 0; n < 4; ++n)
        acc[m][n] = __builtin_amdgcn_mfma_f32_16x16x32_bf16(af[m], bfr[n], acc[m][n], 0, 0, 0);
  };

  const int T = HIDN / 32;   // 64 steps
  stage(ldsb, 0);
  stage(ldsb + 16384, 32);
  for (int t = 0; t < T - 2; ++t) {
    char* cb = ldsb + (t & 1) * 16384;
    PIPE_WAIT4_BAR();
    compute(cb);
    PIPE_POST_BAR();
    stage(cb, (t + 2) * 32);
  }
  PIPE_WAIT4_BAR();
  compute(ldsb + ((T - 2) & 1) * 16384);
  PIPE_POST_BAR();
  PIPE_WAIT0_BAR();
  compute(ldsb + ((T - 1) & 1) * 16384);
  PIPE_POST_BAR();

  const float* b2e = b2 + e * DIMD;
  float bias[4];
#pragma unroll
  for (int n = 0; n < 4; ++n) bias[n] = b2e[n0 + wave_n * 64 + n * 16 + lane16];
#pragma unroll
  for (int m = 0; m < 4; ++m) {
#pragma unroll
    for (int q = 0; q < 4; ++q) {
      int r = m0 + wave_m * 64 + m * 16 + kq4 * 4 + q;
      if (r < cnt_e) {
        int a = list[offe + r];
        float w = tw[a];
        float* yrow = Yw + (size_t)a * DIMD;
#pragma unroll
        for (int n = 0; n < 4; ++n) {
          int col = n0 + wave_n * 64 + n * 16 + lane16;
          yrow[col] = w * (acc[m][n][q] + bias[n]);
        }
      }
    }
  }
}

// ---------- combine: out[n] = Yw[2n] + Yw[2n+1] ----------
__global__ __launch_bounds__(256) void combine_kernel(const float* __restrict__ Yw,
                                                      float* __restrict__ out) {
  int i = (blockIdx.x * 256 + threadIdx.x) * 4;
  int n = i >> 9;
  int d = i & 511;
  float4 a = *reinterpret_cast<const float4*>(Yw + (size_t)(2 * n) * DIMD + d);
  float4 b = *reinterpret_cast<const float4*>(Yw + (size_t)(2 * n + 1) * DIMD + d);
  float4 o;
  o.x = a.x + b.x; o.y = a.y + b.y; o.z = a.z + b.z; o.w = a.w + b.w;
  *reinterpret_cast<float4*>(out + i) = o;
}

extern "C" void kernel_launch(void* const* d_in, const int* in_sizes, int n_in,
                              void* d_out, int out_size, void* d_ws, size_t ws_size,
                              hipStream_t stream) {
  const float* x  = (const float*)d_in[0];
  const float* Wr = (const float*)d_in[1];
  const float* br = (const float*)d_in[2];
  const float* W1 = (const float*)d_in[3];
  const float* b1 = (const float*)d_in[4];
  const float* W2 = (const float*)d_in[5];
  const float* b2 = (const float*)d_in[6];
  float* out = (float*)d_out;

  char* ws = (char*)d_ws;
  unsigned short* xb  = (unsigned short*)ws;  ws += (size_t)NTOK * DIMD * 2;
  unsigned short* w1t = (unsigned short*)ws;  ws += (size_t)NEXP * HIDN * DIMD * 2;
  unsigned short* w2t = (unsigned short*)ws;  ws += (size_t)NEXP * DIMD * HIDN * 2;
  unsigned short* H   = (unsigned short*)ws;  ws += (size_t)NASG * HIDN * 2;
  float* Yw = (float*)ws;                     ws += (size_t)NASG * DIMD * 4;
  float* tw = (float*)ws;                     ws += (size_t)NASG * 4;
  int* tidx = (int*)ws;                       ws += (size_t)NASG * 4;
  int* list = (int*)ws;                       ws += (size_t)NASG * 4;
  int* offp = (int*)ws;                       // off[9]

  transpose_both_kernel<<<dim3(32, 8, 16), 256, 0, stream>>>(W1, W2, w1t, w2t);
  router_kernel<<<NTOK / 4, 256, 0, stream>>>(x, Wr, br, tidx, tw, xb);
  route_pack_kernel<<<1, 1024, 0, stream>>>(tidx, offp, list, out + (size_t)NTOK * DIMD);
  // expert = blockIdx.x -> grid-linear %8 == expert -> XCD-pinned weight panels
  gemm1_kernel<<<dim3(NEXP, HIDN / 128, NASG / 128), 256, 0, stream>>>(xb, w1t, b1, offp, list, H);
  gemm2_kernel<<<dim3(NEXP, DIMD / 128, NASG / 128), 256, 0, stream>>>(H, w2t, b2, offp, list, tw, Yw);
  combine_kernel<<<2048, 256, 0, stream>>>(Yw, out);
}